// Round 2
// baseline (3957.020 us; speedup 1.0000x reference)
//
#include <hip/hip_runtime.h>
#include <math.h>

typedef unsigned short u16;
typedef unsigned int   u32;

// ---------- dtype helpers ----------
__device__ __forceinline__ float b2f(u16 v) { return __uint_as_float(((u32)v) << 16); }
__device__ __forceinline__ u16 f2b(float f) {
    u32 u = __float_as_uint(f);
    u32 r = (u + 0x7FFFu + ((u >> 16) & 1u)) >> 16;   // RNE
    return (u16)r;
}
__device__ __forceinline__ float gload(const void* p, long i, int bf) {
    return bf ? b2f(((const u16*)p)[i]) : ((const float*)p)[i];
}
__device__ __forceinline__ void gstore(void* p, long i, float v, int bf) {
    if (bf) ((u16*)p)[i] = f2b(v);
    else    ((float*)p)[i] = v;
}

// ---------- problem constants ----------
#define BATCH 8
#define CIN   64
#define FH    96
#define FW    320
#define KDET  50
#define NROI  400
#define CROI  69
#define HW    (FH*FW)          // 30720
#define PIX   (BATCH*FH*FW)    // 245760

// ---------- workspace layout (float offsets) ----------
#define WS_HEAT 0L
#define WS_OFF2 737280L
#define WS_SIZ2 1228800L
#define WS_NH   1720320L
#define WS_S1S  2457600L
#define WS_S1I  2458800L
#define WS_CLS  2460000L
#define WS_BOX  2460400L
#define WS_ROI  2462400L
#define WS_HOUT 3814800L
#define WS_W1T  3827600L     // 3 * 576*256 f32 (branch conv1, [k][c])
#define WS_W1H  4269968L     // 4 * 621*256 f32 (head conv1, [k][c])
#define WS_PAR  4905872L     // packed f32 params (33088)
#define WS_FLAG 4938960L     // int dtype flag

// param block sub-offsets
#define PB_CAL 0
#define PB_CRN 96
#define PB_MSZ 128
#define PB_BR0 144          // stride 1040: b1@0, w2@256, b2@256+OC*256
#define PB_HD0 3264         // stride 7456: b1,g,beta,m,v @0..1024, w2@1280, b2@1280+oc*256

// ---------- output layout (element offsets) ----------
#define O_HEAT 0L
#define O_OFF2 737280L
#define O_SIZ2 1228800L
#define O_HEAD 1720320L
#define O_DEP  1729920L
#define O_OFF3 1730720L
#define O_S3D  1731520L
#define O_H3D  1732720L

// =====================================================================
// dtype detection: bf16 arrays -> ~512/512 sane bf16 values;
// f32-reinterpreted -> ~296/512 (low halves of floats are uniform u16)
// =====================================================================
__global__ void kDetect(const void* __restrict__ feat, int* __restrict__ flag) {
    __shared__ int cnt;
    if (threadIdx.x == 0) cnt = 0;
    __syncthreads();
    u16 v = ((const u16*)feat)[threadIdx.x];     // 512 threads
    float f = b2f(v);
    u32 e = (v >> 7) & 0xFF;
    float a = fabsf(f);
    int sane = (e != 0xFF) && (f == 0.f || (a >= 1e-8f && a <= 1e4f));
    atomicAdd(&cnt, sane);
    __syncthreads();
    if (threadIdx.x == 0) *flag = (cnt >= 480) ? 1 : 0;
}

// =====================================================================
// Prep: transpose conv1 weights (c,k)->(k,c) into f32 workspace
// =====================================================================
struct WPtrs { const void* bw[3]; const void* hw[4]; };

__global__ void kPrepW(WPtrs P, const int* __restrict__ flag,
                       float* __restrict__ w1t, float* __restrict__ w1h) {
    const int bf = *flag;
    int idx = blockIdx.x * 256 + threadIdx.x;
    if (idx < 3 * 147456) {
        int br = idx / 147456, rem = idx % 147456;
        int k = rem >> 8, c = rem & 255;
        w1t[idx] = gload(P.bw[br], (long)c * 576 + k, bf);
    } else {
        int j = idx - 3 * 147456;
        if (j < 4 * 158976) {
            int h = j / 158976, rem = j % 158976;
            int k = rem >> 8, c = rem & 255;
            w1h[j] = gload(P.hw[h], (long)c * 621 + k, bf);
        }
    }
}

// Prep: pack all small params to f32
struct Seg { const void* src; int n; int dst; };
struct Segs { Seg s[40]; };

__global__ void kPrepP(Segs S, const int* __restrict__ flag, float* __restrict__ par) {
    const int bf = *flag;
    Seg sg = S.s[blockIdx.x];
    for (int i = threadIdx.x; i < sg.n; i += 256)
        par[sg.dst + i] = gload(sg.src, i, bf);
}

// =====================================================================
// Fused branch: conv3x3(64->256,pad1)+b1+ReLU + conv1x1(256->OC)+b2
// =====================================================================
union BrLds {
    float w[36 * 256];
    float part[32 * 3 * 64];
};

template<int OC>
__global__ __launch_bounds__(256)
void kBranch(const void* __restrict__ feat, const int* __restrict__ flag,
             const float* __restrict__ w1t, const float* __restrict__ bp,
             void* __restrict__ outb, long obase, float* __restrict__ outf) {
    __shared__ float in_lds[4][3][68];
    __shared__ BrLds u;
    const int bf = *flag;

    const int tid = threadIdx.x;
    const int xg = tid & 7, cg = tid >> 3;
    const int x0 = blockIdx.x * 64, y = blockIdx.y, b = blockIdx.z;
    const int c0 = cg * 8;

    float acc[8][8];
#pragma unroll
    for (int i = 0; i < 8; ++i)
#pragma unroll
        for (int j = 0; j < 8; ++j) acc[i][j] = 0.f;

    for (int chunk = 0; chunk < 16; ++chunk) {
        const int ci0 = chunk * 4;
        __syncthreads();
        for (int i = tid; i < 4 * 3 * 68; i += 256) {
            int xx = i % 68, t2 = i / 68;
            int r = t2 % 3, ci = t2 / 3;
            int gx = x0 - 1 + xx, gy = y - 1 + r;
            float v = 0.f;
            if (gx >= 0 && gx < FW && gy >= 0 && gy < FH)
                v = gload(feat, ((long)(b * CIN + ci0 + ci) * FH + gy) * FW + gx, bf);
            in_lds[ci][r][xx] = v;
        }
        {
            const float4* src = (const float4*)(w1t + (long)ci0 * 9 * 256);
            float4* dst = (float4*)u.w;
            for (int i = tid; i < 36 * 256 / 4; i += 256) dst[i] = src[i];
        }
        __syncthreads();
#pragma unroll
        for (int ci = 0; ci < 4; ++ci) {
#pragma unroll
            for (int ky = 0; ky < 3; ++ky) {
                const float* rowp = &in_lds[ci][ky][xg * 8];
                float inv[10];
                *(float4*)&inv[0] = *(const float4*)&rowp[0];
                *(float4*)&inv[4] = *(const float4*)&rowp[4];
                *(float2*)&inv[8] = *(const float2*)&rowp[8];
#pragma unroll
                for (int kx = 0; kx < 3; ++kx) {
                    const float* wp = &u.w[(ci * 9 + ky * 3 + kx) * 256 + c0];
                    float wv[8];
                    *(float4*)&wv[0] = *(const float4*)&wp[0];
                    *(float4*)&wv[4] = *(const float4*)&wp[4];
#pragma unroll
                    for (int cc = 0; cc < 8; ++cc)
#pragma unroll
                        for (int xx = 0; xx < 8; ++xx)
                            acc[cc][xx] = fmaf(wv[cc], inv[xx + kx], acc[cc][xx]);
                }
            }
        }
    }

    // bias + relu
#pragma unroll
    for (int cc = 0; cc < 8; ++cc) {
        float b1v = bp[c0 + cc];
#pragma unroll
        for (int xx = 0; xx < 8; ++xx)
            acc[cc][xx] = fmaxf(acc[cc][xx] + b1v, 0.f);
    }

    __syncthreads();
#pragma unroll
    for (int k = 0; k < OC; ++k) {
        float p[8];
#pragma unroll
        for (int xx = 0; xx < 8; ++xx) p[xx] = 0.f;
#pragma unroll
        for (int cc = 0; cc < 8; ++cc) {
            float wv = bp[256 + k * 256 + c0 + cc];
#pragma unroll
            for (int xx = 0; xx < 8; ++xx) p[xx] = fmaf(acc[cc][xx], wv, p[xx]);
        }
#pragma unroll
        for (int xx = 0; xx < 8; ++xx)
            u.part[(cg * OC + k) * 64 + xg * 8 + xx] = p[xx];
    }
    __syncthreads();
    for (int t = tid; t < OC * 64; t += 256) {
        int k = t >> 6, xx = t & 63;
        float s = bp[256 + OC * 256 + k];
#pragma unroll 8
        for (int g = 0; g < 32; ++g) s += u.part[(g * OC + k) * 64 + xx];
        long o = (((long)b * OC + k) * FH + y) * FW + x0 + xx;
        gstore(outb, obase + o, s, bf);
        outf[o] = s;
    }
}

// =====================================================================
// NMS
// =====================================================================
__global__ void kNms(const float* __restrict__ heat, float* __restrict__ nh) {
    int idx = blockIdx.x * 256 + threadIdx.x;
    if (idx >= 737280) return;
    int x = idx % FW, t = idx / FW;
    int yy = t % FH, bc = t / FH;
    const float* p = heat + (long)bc * HW;
    float v = p[yy * FW + x];
    float m = v;
    for (int dy = -1; dy <= 1; ++dy) {
        int ny = yy + dy;
        if (ny < 0 || ny >= FH) continue;
        for (int dx = -1; dx <= 1; ++dx) {
            int nx = x + dx;
            if (nx < 0 || nx >= FW) continue;
            m = fmaxf(m, p[ny * FW + nx]);
        }
    }
    nh[idx] = (v == m) ? v : 0.f;
}

// =====================================================================
// top-50 stage 1 per (b,c): ties -> smallest index (destructive)
// =====================================================================
__global__ void kTop1(float* __restrict__ nh, float* __restrict__ s1s,
                      int* __restrict__ s1i) {
    __shared__ float rv[256];
    __shared__ int   ri[256];
    const int bc = blockIdx.x, tid = threadIdx.x;
    float* p = nh + (long)bc * HW;
    for (int it = 0; it < KDET; ++it) {
        float bv = -INFINITY; int bi = 0x7fffffff;
        for (int j = tid; j < HW; j += 256) {
            float v = p[j];
            if (v > bv) { bv = v; bi = j; }
        }
        rv[tid] = bv; ri[tid] = bi;
        __syncthreads();
        for (int s = 128; s > 0; s >>= 1) {
            if (tid < s) {
                float v2 = rv[tid + s]; int i2 = ri[tid + s];
                if (v2 > rv[tid] || (v2 == rv[tid] && i2 < ri[tid])) {
                    rv[tid] = v2; ri[tid] = i2;
                }
            }
            __syncthreads();
        }
        if (tid == 0) {
            s1s[bc * KDET + it] = rv[0];
            s1i[bc * KDET + it] = ri[0];
            p[ri[0]] = -INFINITY;
        }
        __syncthreads();
    }
}

// =====================================================================
// top-50 stage 2 + boxes
// =====================================================================
__global__ void kTop2(const float* __restrict__ s1s, const int* __restrict__ s1i,
                      const float* __restrict__ off2, const float* __restrict__ siz2,
                      float* __restrict__ boxes, int* __restrict__ clsArr) {
    const int b = blockIdx.x, t = threadIdx.x;    // 64 threads
    __shared__ float sc[150];
    for (int i = t; i < 150; i += 64) sc[i] = s1s[b * 150 + i];
    __syncthreads();
    for (int r = 0; r < KDET; ++r) {
        float bv = -INFINITY; int bp = 0x7fffffff;
        for (int i = t; i < 150; i += 64) {
            float v = sc[i];
            if (v > bv) { bv = v; bp = i; }
        }
        for (int s = 32; s > 0; s >>= 1) {
            float v2 = __shfl_down(bv, s);
            int   p2 = __shfl_down(bp, s);
            if (v2 > bv || (v2 == bv && p2 < bp)) { bv = v2; bp = p2; }
        }
        if (t == 0) {
            int cls = bp / KDET;
            int ind = s1i[b * 150 + bp];
            int n = b * KDET + r;
            clsArr[n] = cls;
            int x = ind % FW, yy = ind / FW;
            float cx = (float)x  + off2[(((long)b * 2 + 0) * FH + yy) * FW + x];
            float cy = (float)yy + off2[(((long)b * 2 + 1) * FH + yy) * FW + x];
            float w  = siz2[(((long)b * 2 + 0) * FH + yy) * FW + x];
            float h  = siz2[(((long)b * 2 + 1) * FH + yy) * FW + x];
            boxes[n * 5 + 0] = (float)b;
            boxes[n * 5 + 1] = cx - w * 0.5f;
            boxes[n * 5 + 2] = cy - h * 0.5f;
            boxes[n * 5 + 3] = cx + w * 0.5f;
            boxes[n * 5 + 4] = cy + h * 0.5f;
            sc[bp] = -INFINITY;
        }
        __syncthreads();
    }
}

// =====================================================================
// ROI align 7x7 (sr=2) + coord maps + one-hot -> roi_in f32
// =====================================================================
__global__ __launch_bounds__(256)
void kRoi(const void* __restrict__ feat, const int* __restrict__ flag,
          const float* __restrict__ boxes, const int* __restrict__ clsArr,
          const float* __restrict__ par, float* __restrict__ roi_in) {
    const int n = blockIdx.x, tid = threadIdx.x;
    const int bf = *flag;
    __shared__ int   x0s[14], x1s[14], y0s[14], y1s[14], vxs[14], vys[14];
    __shared__ float lxs[14], lys[14], cxs[7], cys[7];

    const float bx1 = boxes[n * 5 + 1], by1 = boxes[n * 5 + 2];
    const float bx2 = boxes[n * 5 + 3], by2 = boxes[n * 5 + 4];
    const int b = (int)boxes[n * 5 + 0];

    if (tid < 14) {
        float roi_w = fmaxf(bx2 - bx1, 1.f);
        float X = bx1 + (roi_w / 7.f) * ((tid + 0.5f) * 0.5f);
        vxs[tid] = (X > -1.f) && (X < (float)FW);
        float Xc = fminf(fmaxf(X, 0.f), (float)(FW - 1));
        int xi = (int)floorf(Xc);
        x0s[tid] = xi; x1s[tid] = min(xi + 1, FW - 1); lxs[tid] = Xc - (float)xi;
    } else if (tid >= 16 && tid < 30) {
        int i = tid - 16;
        float roi_h = fmaxf(by2 - by1, 1.f);
        float Y = by1 + (roi_h / 7.f) * ((i + 0.5f) * 0.5f);
        vys[i] = (Y > -1.f) && (Y < (float)FH);
        float Yc = fminf(fmaxf(Y, 0.f), (float)(FH - 1));
        int yi = (int)floorf(Yc);
        y0s[i] = yi; y1s[i] = min(yi + 1, FH - 1); lys[i] = Yc - (float)yi;
    } else if (tid >= 32 && tid < 46) {
        int j = tid - 32;
        const float* cal = par + PB_CAL + b * 12;
        float f_u = cal[0], c_u = cal[2], t03 = cal[3];
        float f_v = cal[5], c_v = cal[6], t13 = cal[7];
        float bxc = t03 / (-f_u), byc = t13 / (-f_v);
        const float* cr = par + PB_CRN + b * 4;
        float crx0 = cr[0], cry0 = cr[1], crx1 = cr[2], cry1 = cr[3];
        float sx = crx1 - crx0, sy = cry1 - cry0;
        float u1 = bx1 / (float)FW * sx + crx0, v1 = by1 / (float)FH * sy + cry0;
        float u2 = bx2 / (float)FW * sx + crx0, v2 = by2 / (float)FH * sy + cry0;
        float p1x = (u1 - c_u) / f_u + bxc, p1y = (v1 - c_v) / f_v + byc;
        float p2x = (u2 - c_u) / f_u + bxc, p2y = (v2 - c_v) / f_v + byc;
        if (j < 7) cxs[j] = p1x + ((float)j / 6.f) * (p2x - p1x);
        else       cys[j - 7] = p1y + ((float)(j - 7) / 6.f) * (p2y - p1y);
    }
    __syncthreads();

    for (int t = tid; t < CIN * 49; t += 256) {
        int c = t / 49, p = t % 49, oy = p / 7, ox = p % 7;
        long fb = ((long)b * CIN + c) * HW;
        float acc = 0.f;
#pragma unroll
        for (int dy = 0; dy < 2; ++dy) {
            int sy = oy * 2 + dy;
            float ly = lys[sy]; int yA = y0s[sy], yB = y1s[sy], vy = vys[sy];
#pragma unroll
            for (int dx = 0; dx < 2; ++dx) {
                int sx = ox * 2 + dx;
                float lx = lxs[sx]; int xA = x0s[sx], xB = x1s[sx];
                float v = (1.f - ly) * (1.f - lx) * gload(feat, fb + yA * FW + xA, bf)
                        + (1.f - ly) * lx         * gload(feat, fb + yA * FW + xB, bf)
                        + ly * (1.f - lx)         * gload(feat, fb + yB * FW + xA, bf)
                        + ly * lx                 * gload(feat, fb + yB * FW + xB, bf);
                if (!(vy && vxs[sx])) v = 0.f;
                acc += v;
            }
        }
        roi_in[((long)n * CROI + c) * 49 + p] = acc * 0.25f;
    }
    int cls = clsArr[n];
    for (int t = tid; t < 5 * 49; t += 256) {
        int ch = t / 49, p = t % 49, i = p / 7, j = p % 7;
        float v;
        if (ch == 0)      v = cxs[j];
        else if (ch == 1) v = cys[i];
        else              v = (cls == ch - 2) ? 1.f : 0.f;
        roi_in[((long)n * CROI + 64 + ch) * 49 + p] = v;
    }
}

// =====================================================================
// ROI head: conv3x3(69->256,pad1)+b1 -> BN -> relu -> mean -> 1x1
// =====================================================================
__global__ __launch_bounds__(256)
void kHead(const float* __restrict__ roi_in, const float* __restrict__ w1h,
           const float* __restrict__ par, float* __restrict__ head_out) {
    const int h = blockIdx.x, n = blockIdx.y, tid = threadIdx.x;
    const int ocArr[4] = {2, 2, 4, 24};
    const int offArr[4] = {0, 2, 4, 8};
    __shared__ float in_lds[CROI][9][12];
    __shared__ float means[256];

    float* il = &in_lds[0][0][0];
    for (int i = tid; i < CROI * 9 * 12; i += 256) il[i] = 0.f;
    __syncthreads();
    for (int i = tid; i < CROI * 49; i += 256) {
        int c = i / 49, p = i % 49, oy = p / 7, ox = p % 7;
        in_lds[c][oy + 1][ox + 1] = roi_in[((long)n * CROI + c) * 49 + p];
    }
    __syncthreads();

    float acc[49];
#pragma unroll
    for (int p = 0; p < 49; ++p) acc[p] = 0.f;

    const float* wsrc = w1h + (long)h * 158976;
    for (int ci = 0; ci < CROI; ++ci) {
        float wv[9];
#pragma unroll
        for (int j = 0; j < 9; ++j) wv[j] = wsrc[(ci * 9 + j) * 256 + tid];
#pragma unroll
        for (int r = 0; r < 9; ++r) {
            float4 q0 = *(const float4*)&in_lds[ci][r][0];
            float4 q1 = *(const float4*)&in_lds[ci][r][4];
            float4 q2 = *(const float4*)&in_lds[ci][r][8];
            float row[12] = {q0.x, q0.y, q0.z, q0.w, q1.x, q1.y, q1.z, q1.w,
                             q2.x, q2.y, q2.z, q2.w};
#pragma unroll
            for (int ky = 0; ky < 3; ++ky) {
                int oy = r - ky;
                if (oy >= 0 && oy <= 6) {
#pragma unroll
                    for (int ox = 0; ox < 7; ++ox)
#pragma unroll
                        for (int kx = 0; kx < 3; ++kx)
                            acc[oy * 7 + ox] =
                                fmaf(row[ox + kx], wv[ky * 3 + kx], acc[oy * 7 + ox]);
                }
            }
        }
    }

    const float* hb = par + PB_HD0 + h * 7456;
    float b1v = hb[tid], gv = hb[256 + tid], bev = hb[512 + tid];
    float mv = hb[768 + tid], vv = hb[1024 + tid];
    float scale = gv / sqrtf(vv + 1e-5f);
    float s = 0.f;
#pragma unroll
    for (int p = 0; p < 49; ++p)
        s += fmaxf((acc[p] + b1v - mv) * scale + bev, 0.f);
    means[tid] = s / 49.f;
    __syncthreads();
    int oc = ocArr[h];
    if (tid < oc) {
        float o = hb[1280 + oc * 256 + tid];            // b2
        for (int c = 0; c < 256; ++c) o += means[c] * hb[1280 + tid * 256 + c];
        head_out[(long)n * 32 + offArr[h] + tid] = o;
    }
}

// =====================================================================
// Final scalar math + small outputs
// =====================================================================
__global__ void kFinal(const float* __restrict__ head_out, const float* __restrict__ boxes,
                       const int* __restrict__ clsArr, const float* __restrict__ par,
                       void* __restrict__ out, const int* __restrict__ flag) {
    int n = blockIdx.x * 256 + threadIdx.x;
    if (n >= NROI) return;
    const int bf = *flag;
    const float* ho = head_out + (long)n * 32;
    float dep0 = ho[0], dep1 = ho[1];
    int b = (int)boxes[n * 5 + 0];
    int cls = clsArr[n];

    for (int j = 0; j < 24; ++j) gstore(out, O_HEAD + n * 24 + j, ho[8 + j], bf);
    gstore(out, O_OFF3 + n * 2 + 0, ho[2], bf);
    gstore(out, O_OFF3 + n * 2 + 1, ho[3], bf);
    gstore(out, O_S3D + n * 3 + 0, ho[4], bf);
    gstore(out, O_S3D + n * 3 + 1, ho[5], bf);
    gstore(out, O_S3D + n * 3 + 2, ho[6], bf);
    gstore(out, O_H3D + n, ho[7], bf);

    float cry0 = par[PB_CRN + b * 4 + 1], cry1 = par[PB_CRN + b * 4 + 3];
    float sy = cry1 - cry0;
    float bi2 = boxes[n * 5 + 2] / (float)FH * sy + cry0;
    float bi4 = boxes[n * 5 + 4] / (float)FH * sy + cry0;
    float box_h = fmaxf(bi4 - bi2, 1.f);
    float f_u = par[PB_CAL + b * 12 + 0];
    float size3d0 = par[PB_MSZ + cls * 3 + 0] + ho[4];
    float depth_geo = size3d0 / box_h * f_u;
    float sig = 1.f / (1.f + expf(-dep0));
    float d0 = 1.f / (sig + 1e-6f) - 1.f + depth_geo;
    float dgls = ho[7] + 2.f * (logf(f_u) - logf(box_h));
    float mx = fmaxf(dep1, dgls);
    float lse = mx + logf(expf(dep1 - mx) + expf(dgls - mx));
    gstore(out, O_DEP + n * 2 + 0, d0, bf);
    gstore(out, O_DEP + n * 2 + 1, lse, bf);
}

// =====================================================================
extern "C" void kernel_launch(void* const* d_in, const int* in_sizes, int n_in,
                              void* d_out, int out_size, void* d_ws, size_t ws_size,
                              hipStream_t stream) {
    (void)in_sizes; (void)n_in; (void)out_size; (void)ws_size;
    float* ws = (float*)d_ws;
    float* par = ws + WS_PAR;
    int* flag = (int*)(ws + WS_FLAG);
    const void* feat = d_in[0];

    kDetect<<<1, 512, 0, stream>>>(feat, flag);

    WPtrs WP;
    WP.bw[0] = d_in[4]; WP.bw[1] = d_in[8]; WP.bw[2] = d_in[12];
    WP.hw[0] = d_in[16]; WP.hw[1] = d_in[24]; WP.hw[2] = d_in[32]; WP.hw[3] = d_in[40];
    kPrepW<<<4212, 256, 0, stream>>>(WP, flag, ws + WS_W1T, ws + WS_W1H);

    Segs SG; int si = 0;
    auto add = [&](const void* s, int n, int dst) {
        SG.s[si].src = s; SG.s[si].n = n; SG.s[si].dst = dst; ++si;
    };
    add(d_in[1], 96, PB_CAL); add(d_in[2], 32, PB_CRN); add(d_in[3], 9, PB_MSZ);
    const int ocb[3] = {3, 2, 2};
    for (int b = 0; b < 3; ++b) {
        int base = PB_BR0 + b * 1040;
        int i0 = 4 + 4 * b;                       // w1,b1,w2,b2
        add(d_in[i0 + 1], 256, base);
        add(d_in[i0 + 2], ocb[b] * 256, base + 256);
        add(d_in[i0 + 3], ocb[b], base + 256 + ocb[b] * 256);
    }
    const int och[4] = {2, 2, 4, 24};
    for (int h = 0; h < 4; ++h) {
        int base = PB_HD0 + h * 7456;
        int i0 = 16 + 8 * h;                      // w1,b1,g,beta,m,v,w2,b2
        add(d_in[i0 + 1], 256, base);
        add(d_in[i0 + 2], 256, base + 256);
        add(d_in[i0 + 3], 256, base + 512);
        add(d_in[i0 + 4], 256, base + 768);
        add(d_in[i0 + 5], 256, base + 1024);
        add(d_in[i0 + 6], och[h] * 256, base + 1280);
        add(d_in[i0 + 7], och[h], base + 1280 + och[h] * 256);
    }
    kPrepP<<<si, 256, 0, stream>>>(SG, flag, par);

    kBranch<3><<<dim3(5, 96, 8), 256, 0, stream>>>(
        feat, flag, ws + WS_W1T, par + PB_BR0, d_out, O_HEAT, ws + WS_HEAT);
    kBranch<2><<<dim3(5, 96, 8), 256, 0, stream>>>(
        feat, flag, ws + WS_W1T + 147456, par + PB_BR0 + 1040, d_out, O_OFF2, ws + WS_OFF2);
    kBranch<2><<<dim3(5, 96, 8), 256, 0, stream>>>(
        feat, flag, ws + WS_W1T + 294912, par + PB_BR0 + 2080, d_out, O_SIZ2, ws + WS_SIZ2);

    kNms<<<2880, 256, 0, stream>>>(ws + WS_HEAT, ws + WS_NH);
    kTop1<<<24, 256, 0, stream>>>(ws + WS_NH, ws + WS_S1S, (int*)(ws + WS_S1I));
    kTop2<<<8, 64, 0, stream>>>(ws + WS_S1S, (int*)(ws + WS_S1I), ws + WS_OFF2,
                                ws + WS_SIZ2, ws + WS_BOX, (int*)(ws + WS_CLS));
    kRoi<<<400, 256, 0, stream>>>(feat, flag, ws + WS_BOX, (int*)(ws + WS_CLS),
                                  par, ws + WS_ROI);
    kHead<<<dim3(4, NROI), 256, 0, stream>>>(ws + WS_ROI, ws + WS_W1H, par, ws + WS_HOUT);
    kFinal<<<2, 256, 0, stream>>>(ws + WS_HOUT, ws + WS_BOX, (int*)(ws + WS_CLS),
                                  par, d_out, flag);
}

// Round 3
// 2094.857 us; speedup vs baseline: 1.8889x; 1.8889x over previous
//
#include <hip/hip_runtime.h>
#include <math.h>

typedef unsigned short u16;
typedef unsigned int   u32;
typedef __attribute__((ext_vector_type(8))) short short8;   // 8 bf16 (4 VGPR)
typedef __attribute__((ext_vector_type(4))) float f32x4;    // MFMA acc

// ---------- dtype helpers ----------
__device__ __forceinline__ float b2f(u16 v) { return __uint_as_float(((u32)v) << 16); }
__device__ __forceinline__ u16 f2b(float f) {
    u32 u = __float_as_uint(f);
    u32 r = (u + 0x7FFFu + ((u >> 16) & 1u)) >> 16;   // RNE
    return (u16)r;
}
__device__ __forceinline__ float gload(const void* p, long i, int bf) {
    return bf ? b2f(((const u16*)p)[i]) : ((const float*)p)[i];
}
__device__ __forceinline__ void gstore(void* p, long i, float v, int bf) {
    if (bf) ((u16*)p)[i] = f2b(v);
    else    ((float*)p)[i] = v;
}

// ---------- problem constants ----------
#define BATCH 8
#define CIN   64
#define FH    96
#define FW    320
#define KDET  50
#define NROI  400
#define CROI  69
#define HW    (FH*FW)

// ---------- workspace layout (float offsets) ----------
#define WS_HEAT 0L
#define WS_OFF2 737280L
#define WS_SIZ2 1228800L
#define WS_NH   1720320L
#define WS_S1S  2457600L
#define WS_S1I  2458800L
#define WS_CLS  2460000L
#define WS_BOX  2460400L
#define WS_ROI  2462400L
#define WS_HOUT 3814800L
#define WS_W1T  3827600L     // 147456 f32: hm conv1 [k=576][c=256] (exact strip)
#define WS_WB16 3975056L     // u16 region: 3 branches * [9][256][64] bf16 = 442368 u16
#define WS_W1H  4269968L     // 4 * 621*256 f32 (head conv1, [k][c])
#define WS_PAR  4905872L     // packed f32 params
#define WS_FLAG 4938960L     // int dtype flag

// param block sub-offsets
#define PB_CAL 0
#define PB_CRN 96
#define PB_MSZ 128
#define PB_BR0 144          // stride 1040: b1@0, w2@256 ([k][n]), b2@256+OC*256
#define PB_HD0 3264         // stride 7456

// ---------- output layout (element offsets) ----------
#define O_HEAT 0L
#define O_OFF2 737280L
#define O_SIZ2 1228800L
#define O_HEAD 1720320L
#define O_DEP  1729920L
#define O_OFF3 1730720L
#define O_S3D  1731520L
#define O_H3D  1732720L

// =====================================================================
// dtype detection
// =====================================================================
__global__ void kDetect(const void* __restrict__ feat, int* __restrict__ flag) {
    __shared__ int cnt;
    if (threadIdx.x == 0) cnt = 0;
    __syncthreads();
    u16 v = ((const u16*)feat)[threadIdx.x];     // 512 threads
    float f = b2f(v);
    u32 e = (v >> 7) & 0xFF;
    float a = fabsf(f);
    int sane = (e != 0xFF) && (f == 0.f || (a >= 1e-8f && a <= 1e4f));
    atomicAdd(&cnt, sane);
    __syncthreads();
    if (threadIdx.x == 0) *flag = (cnt >= 480) ? 1 : 0;
}

// =====================================================================
// Prep: weights
//  region 1: hm conv1 f32 [k=576][c=256]         (exact strip)
//  region 2: 3 branches bf16 [tap][n=256][ci=64] (MFMA B operand)
//  region 3: head conv1 f32 [k=621][c=256]
// =====================================================================
struct WPtrs { const void* bw[3]; const void* hw[4]; };

__global__ void kPrepW(WPtrs P, const int* __restrict__ flag,
                       float* __restrict__ w1t, u16* __restrict__ wb16,
                       float* __restrict__ w1h) {
    const int bf = *flag;
    int idx = blockIdx.x * 256 + threadIdx.x;
    if (idx < 147456) {
        int k = idx >> 8, c = idx & 255;
        w1t[idx] = gload(P.bw[0], (long)c * 576 + k, bf);
    } else if (idx < 147456 + 442368) {
        int j = idx - 147456;
        int br = j / 147456, rem = j % 147456;
        int tap = rem / 16384, n = (rem >> 6) & 255, ci = rem & 63;
        wb16[j] = f2b(gload(P.bw[br], (long)n * 576 + ci * 9 + tap, bf));
    } else {
        int j = idx - 147456 - 442368;
        if (j < 4 * 158976) {
            int h = j / 158976, rem = j % 158976;
            int k = rem >> 8, c = rem & 255;
            w1h[j] = gload(P.hw[h], (long)c * 621 + k, bf);
        }
    }
}

// Prep: pack all small params to f32
struct Seg { const void* src; int n; int dst; };
struct Segs { Seg s[40]; };

__global__ void kPrepP(Segs S, const int* __restrict__ flag, float* __restrict__ par) {
    const int bf = *flag;
    Seg sg = S.s[blockIdx.x];
    for (int i = threadIdx.x; i < sg.n; i += 256)
        par[sg.dst + i] = gload(sg.src, i, bf);
}

// =====================================================================
// MFMA branch: conv3x3(64->256) as 9 shifted GEMMs + b1 + ReLU + 1x1 + b2
// Block: 256 thr = 4 waves; tile = row y, 64 x, 256 hidden.
// wave w: n in [w*64, w*64+64); 4x4 tiles of mfma 16x16x32 bf16.
// =====================================================================
template<int OC>
__global__ __launch_bounds__(256, 2)
void kBranchM(const void* __restrict__ feat, const int* __restrict__ flag,
              const u16* __restrict__ wb,     // [9][256][64] bf16
              const float* __restrict__ bp,   // b1, w2[k][n], b2
              void* __restrict__ outb, long obase, float* __restrict__ outf) {
    __shared__ __align__(16) u16 a_lds[3][68][72];
    __shared__ __align__(16) u16 w_lds[256][72];
    __shared__ float red[4][64][OC];

    const int bfl = *flag;
    const int tid = threadIdx.x;
    const int wave = tid >> 6, lane = tid & 63;
    const int q = lane >> 4, n15 = lane & 15;
    const int x0 = blockIdx.x * 64, y = blockIdx.y, b = blockIdx.z;
    const int n0 = wave * 64;

    // ---- stage input tile: rows y-1..y+1, x0-1..x0+64, 64 ci (bf16) ----
    if (tid < 192) {
        const int ci = tid & 63, r = tid >> 6;
        const int gy = y - 1 + r;
        if (gy < 0 || gy >= FH) {
            for (int xi = 0; xi < 66; ++xi) a_lds[r][xi][ci] = 0;
        } else if (bfl) {
            const u16* rp = (const u16*)feat + ((long)((b << 6) | ci) * FH + gy) * FW;
            for (int j = 0; j < 10; ++j) {
                int xs0 = x0 - 8 + j * 8;
                u16 tmp[8];
                if (xs0 >= 0 && xs0 <= FW - 8)
                    *(uint4*)tmp = *(const uint4*)(rp + xs0);
                else
                    for (int e = 0; e < 8; ++e) {
                        int gx = xs0 + e;
                        tmp[e] = (gx >= 0 && gx < FW) ? rp[gx] : (u16)0;
                    }
                for (int e = 0; e < 8; ++e) {
                    int xi = xs0 + e - x0 + 1;
                    if (xi >= 0 && xi < 66) a_lds[r][xi][ci] = tmp[e];
                }
            }
        } else {
            const float* rp = (const float*)feat + ((long)((b << 6) | ci) * FH + gy) * FW;
            for (int j = 0; j < 18; ++j) {
                int xs0 = x0 - 4 + j * 4;
                float tmp[4];
                if (xs0 >= 0 && xs0 <= FW - 4)
                    *(float4*)tmp = *(const float4*)(rp + xs0);
                else
                    for (int e = 0; e < 4; ++e) {
                        int gx = xs0 + e;
                        tmp[e] = (gx >= 0 && gx < FW) ? rp[gx] : 0.f;
                    }
                for (int e = 0; e < 4; ++e) {
                    int xi = xs0 + e - x0 + 1;
                    if (xi >= 0 && xi < 66) a_lds[r][xi][ci] = f2b(tmp[e]);
                }
            }
        }
    }

    f32x4 acc[4][4];
#pragma unroll
    for (int i = 0; i < 4; ++i)
#pragma unroll
        for (int t = 0; t < 4; ++t) acc[i][t] = (f32x4){0.f, 0.f, 0.f, 0.f};

    // ---- K-loop: 9 taps x 2 k-steps (32 ci each) ----
    for (int tap = 0; tap < 9; ++tap) {
        __syncthreads();
        const u16* wt = wb + tap * 16384;
        for (int i = tid; i < 2048; i += 256) {
            int n = i >> 3, c8 = i & 7;
            *(uint4*)&w_lds[n][c8 * 8] = *(const uint4*)(wt + n * 64 + c8 * 8);
        }
        __syncthreads();
        const int ky = tap / 3, kx = tap % 3;
#pragma unroll
        for (int s = 0; s < 2; ++s) {
            short8 afr[4], bfr[4];
#pragma unroll
            for (int i = 0; i < 4; ++i)
                afr[i] = *(const short8*)&a_lds[ky][i * 16 + n15 + kx][s * 32 + q * 8];
#pragma unroll
            for (int t = 0; t < 4; ++t)
                bfr[t] = *(const short8*)&w_lds[n0 + t * 16 + n15][s * 32 + q * 8];
#pragma unroll
            for (int i = 0; i < 4; ++i)
#pragma unroll
                for (int t = 0; t < 4; ++t)
                    acc[i][t] = __builtin_amdgcn_mfma_f32_16x16x32_bf16(
                        afr[i], bfr[t], acc[i][t], 0, 0, 0);
        }
    }

    // ---- epilogue: b1 + relu + 1x1 partials, reduce over n ----
    float b1v[4], w2v[OC][4];
#pragma unroll
    for (int t = 0; t < 4; ++t) {
        int n = n0 + t * 16 + n15;
        b1v[t] = bp[n];
#pragma unroll
        for (int k = 0; k < OC; ++k) w2v[k][t] = bp[256 + k * 256 + n];
    }
#pragma unroll
    for (int i = 0; i < 4; ++i) {
#pragma unroll
        for (int r = 0; r < 4; ++r) {
            float pk[OC];
#pragma unroll
            for (int k = 0; k < OC; ++k) pk[k] = 0.f;
#pragma unroll
            for (int t = 0; t < 4; ++t) {
                float h = fmaxf(acc[i][t][r] + b1v[t], 0.f);
#pragma unroll
                for (int k = 0; k < OC; ++k) pk[k] = fmaf(h, w2v[k][t], pk[k]);
            }
#pragma unroll
            for (int k = 0; k < OC; ++k) {
                pk[k] += __shfl_xor(pk[k], 1);
                pk[k] += __shfl_xor(pk[k], 2);
                pk[k] += __shfl_xor(pk[k], 4);
                pk[k] += __shfl_xor(pk[k], 8);
            }
            if (n15 == 0) {
#pragma unroll
                for (int k = 0; k < OC; ++k)
                    red[wave][i * 16 + q * 4 + r][k] = pk[k];
            }
        }
    }
    __syncthreads();
    if (tid < 64 * OC) {
        int k = tid >> 6, px = tid & 63;
        float s = bp[256 + OC * 256 + k];
#pragma unroll
        for (int w = 0; w < 4; ++w) s += red[w][px][k];
        long o = (((long)b * OC + k) * FH + y) * FW + x0 + px;
        gstore(outb, obase + o, s, bfl);
        outf[o] = s;
    }
}

// =====================================================================
// Exact f32 strip (rows 0..4 of heat): NMS/topk decisions bit-match f32
// =====================================================================
union BrLds {
    float w[36 * 256];
    float part[32 * 3 * 64];
};

__global__ __launch_bounds__(256)
void kBranchX(const void* __restrict__ feat, const int* __restrict__ flag,
              const float* __restrict__ w1t, const float* __restrict__ bp,
              void* __restrict__ outb, long obase, float* __restrict__ outf) {
    __shared__ float in_lds[4][3][68];
    __shared__ BrLds u;
    const int bf = *flag;
    const int OC = 3;

    const int tid = threadIdx.x;
    const int xg = tid & 7, cg = tid >> 3;
    const int x0 = blockIdx.x * 64, y = blockIdx.y, b = blockIdx.z;
    const int c0 = cg * 8;

    float acc[8][8];
#pragma unroll
    for (int i = 0; i < 8; ++i)
#pragma unroll
        for (int j = 0; j < 8; ++j) acc[i][j] = 0.f;

    for (int chunk = 0; chunk < 16; ++chunk) {
        const int ci0 = chunk * 4;
        __syncthreads();
        for (int i = tid; i < 4 * 3 * 68; i += 256) {
            int xx = i % 68, t2 = i / 68;
            int r = t2 % 3, ci = t2 / 3;
            int gx = x0 - 1 + xx, gy = y - 1 + r;
            float v = 0.f;
            if (gx >= 0 && gx < FW && gy >= 0 && gy < FH)
                v = gload(feat, ((long)(b * CIN + ci0 + ci) * FH + gy) * FW + gx, bf);
            in_lds[ci][r][xx] = v;
        }
        {
            const float4* src = (const float4*)(w1t + (long)ci0 * 9 * 256);
            float4* dst = (float4*)u.w;
            for (int i = tid; i < 36 * 256 / 4; i += 256) dst[i] = src[i];
        }
        __syncthreads();
#pragma unroll
        for (int ci = 0; ci < 4; ++ci) {
#pragma unroll
            for (int ky = 0; ky < 3; ++ky) {
                const float* rowp = &in_lds[ci][ky][xg * 8];
                float inv[10];
                *(float4*)&inv[0] = *(const float4*)&rowp[0];
                *(float4*)&inv[4] = *(const float4*)&rowp[4];
                *(float2*)&inv[8] = *(const float2*)&rowp[8];
#pragma unroll
                for (int kx = 0; kx < 3; ++kx) {
                    const float* wp = &u.w[(ci * 9 + ky * 3 + kx) * 256 + c0];
                    float wv[8];
                    *(float4*)&wv[0] = *(const float4*)&wp[0];
                    *(float4*)&wv[4] = *(const float4*)&wp[4];
#pragma unroll
                    for (int cc = 0; cc < 8; ++cc)
#pragma unroll
                        for (int xx = 0; xx < 8; ++xx)
                            acc[cc][xx] = fmaf(wv[cc], inv[xx + kx], acc[cc][xx]);
                }
            }
        }
    }

#pragma unroll
    for (int cc = 0; cc < 8; ++cc) {
        float b1v = bp[c0 + cc];
#pragma unroll
        for (int xx = 0; xx < 8; ++xx)
            acc[cc][xx] = fmaxf(acc[cc][xx] + b1v, 0.f);
    }

    __syncthreads();
#pragma unroll
    for (int k = 0; k < OC; ++k) {
        float p[8];
#pragma unroll
        for (int xx = 0; xx < 8; ++xx) p[xx] = 0.f;
#pragma unroll
        for (int cc = 0; cc < 8; ++cc) {
            float wv = bp[256 + k * 256 + c0 + cc];
#pragma unroll
            for (int xx = 0; xx < 8; ++xx) p[xx] = fmaf(acc[cc][xx], wv, p[xx]);
        }
#pragma unroll
        for (int xx = 0; xx < 8; ++xx)
            u.part[(cg * OC + k) * 64 + xg * 8 + xx] = p[xx];
    }
    __syncthreads();
    for (int t = tid; t < OC * 64; t += 256) {
        int k = t >> 6, xx = t & 63;
        float s = bp[256 + OC * 256 + k];
#pragma unroll 8
        for (int g = 0; g < 32; ++g) s += u.part[(g * OC + k) * 64 + xx];
        long o = (((long)b * OC + k) * FH + y) * FW + x0 + xx;
        gstore(outb, obase + o, s, bf);
        outf[o] = s;
    }
}

// =====================================================================
// NMS
// =====================================================================
__global__ void kNms(const float* __restrict__ heat, float* __restrict__ nh) {
    int idx = blockIdx.x * 256 + threadIdx.x;
    if (idx >= 737280) return;
    int x = idx % FW, t = idx / FW;
    int yy = t % FH, bc = t / FH;
    const float* p = heat + (long)bc * HW;
    float v = p[yy * FW + x];
    float m = v;
    for (int dy = -1; dy <= 1; ++dy) {
        int ny = yy + dy;
        if (ny < 0 || ny >= FH) continue;
        for (int dx = -1; dx <= 1; ++dx) {
            int nx = x + dx;
            if (nx < 0 || nx >= FW) continue;
            m = fmaxf(m, p[ny * FW + nx]);
        }
    }
    nh[idx] = (v == m) ? v : 0.f;
}

// =====================================================================
// top-50 stage 1 per (b,c): ties -> smallest index (destructive)
// =====================================================================
__global__ void kTop1(float* __restrict__ nh, float* __restrict__ s1s,
                      int* __restrict__ s1i) {
    __shared__ float rv[256];
    __shared__ int   ri[256];
    const int bc = blockIdx.x, tid = threadIdx.x;
    float* p = nh + (long)bc * HW;
    for (int it = 0; it < KDET; ++it) {
        float bv = -INFINITY; int bi = 0x7fffffff;
        for (int j = tid; j < HW; j += 256) {
            float v = p[j];
            if (v > bv) { bv = v; bi = j; }
        }
        rv[tid] = bv; ri[tid] = bi;
        __syncthreads();
        for (int s = 128; s > 0; s >>= 1) {
            if (tid < s) {
                float v2 = rv[tid + s]; int i2 = ri[tid + s];
                if (v2 > rv[tid] || (v2 == rv[tid] && i2 < ri[tid])) {
                    rv[tid] = v2; ri[tid] = i2;
                }
            }
            __syncthreads();
        }
        if (tid == 0) {
            s1s[bc * KDET + it] = rv[0];
            s1i[bc * KDET + it] = ri[0];
            p[ri[0]] = -INFINITY;
        }
        __syncthreads();
    }
}

// =====================================================================
// top-50 stage 2 + boxes
// =====================================================================
__global__ void kTop2(const float* __restrict__ s1s, const int* __restrict__ s1i,
                      const float* __restrict__ off2, const float* __restrict__ siz2,
                      float* __restrict__ boxes, int* __restrict__ clsArr) {
    const int b = blockIdx.x, t = threadIdx.x;    // 64 threads
    __shared__ float sc[150];
    for (int i = t; i < 150; i += 64) sc[i] = s1s[b * 150 + i];
    __syncthreads();
    for (int r = 0; r < KDET; ++r) {
        float bv = -INFINITY; int bp = 0x7fffffff;
        for (int i = t; i < 150; i += 64) {
            float v = sc[i];
            if (v > bv) { bv = v; bp = i; }
        }
        for (int s = 32; s > 0; s >>= 1) {
            float v2 = __shfl_down(bv, s);
            int   p2 = __shfl_down(bp, s);
            if (v2 > bv || (v2 == bv && p2 < bp)) { bv = v2; bp = p2; }
        }
        if (t == 0) {
            int cls = bp / KDET;
            int ind = s1i[b * 150 + bp];
            int n = b * KDET + r;
            clsArr[n] = cls;
            int x = ind % FW, yy = ind / FW;
            float cx = (float)x  + off2[(((long)b * 2 + 0) * FH + yy) * FW + x];
            float cy = (float)yy + off2[(((long)b * 2 + 1) * FH + yy) * FW + x];
            float w  = siz2[(((long)b * 2 + 0) * FH + yy) * FW + x];
            float h  = siz2[(((long)b * 2 + 1) * FH + yy) * FW + x];
            boxes[n * 5 + 0] = (float)b;
            boxes[n * 5 + 1] = cx - w * 0.5f;
            boxes[n * 5 + 2] = cy - h * 0.5f;
            boxes[n * 5 + 3] = cx + w * 0.5f;
            boxes[n * 5 + 4] = cy + h * 0.5f;
            sc[bp] = -INFINITY;
        }
        __syncthreads();
    }
}

// =====================================================================
// ROI align 7x7 (sr=2) + coord maps + one-hot -> roi_in f32
// =====================================================================
__global__ __launch_bounds__(256)
void kRoi(const void* __restrict__ feat, const int* __restrict__ flag,
          const float* __restrict__ boxes, const int* __restrict__ clsArr,
          const float* __restrict__ par, float* __restrict__ roi_in) {
    const int n = blockIdx.x, tid = threadIdx.x;
    const int bf = *flag;
    __shared__ int   x0s[14], x1s[14], y0s[14], y1s[14], vxs[14], vys[14];
    __shared__ float lxs[14], lys[14], cxs[7], cys[7];

    const float bx1 = boxes[n * 5 + 1], by1 = boxes[n * 5 + 2];
    const float bx2 = boxes[n * 5 + 3], by2 = boxes[n * 5 + 4];
    const int b = (int)boxes[n * 5 + 0];

    if (tid < 14) {
        float roi_w = fmaxf(bx2 - bx1, 1.f);
        float X = bx1 + (roi_w / 7.f) * ((tid + 0.5f) * 0.5f);
        vxs[tid] = (X > -1.f) && (X < (float)FW);
        float Xc = fminf(fmaxf(X, 0.f), (float)(FW - 1));
        int xi = (int)floorf(Xc);
        x0s[tid] = xi; x1s[tid] = min(xi + 1, FW - 1); lxs[tid] = Xc - (float)xi;
    } else if (tid >= 16 && tid < 30) {
        int i = tid - 16;
        float roi_h = fmaxf(by2 - by1, 1.f);
        float Y = by1 + (roi_h / 7.f) * ((i + 0.5f) * 0.5f);
        vys[i] = (Y > -1.f) && (Y < (float)FH);
        float Yc = fminf(fmaxf(Y, 0.f), (float)(FH - 1));
        int yi = (int)floorf(Yc);
        y0s[i] = yi; y1s[i] = min(yi + 1, FH - 1); lys[i] = Yc - (float)yi;
    } else if (tid >= 32 && tid < 46) {
        int j = tid - 32;
        const float* cal = par + PB_CAL + b * 12;
        float f_u = cal[0], c_u = cal[2], t03 = cal[3];
        float f_v = cal[5], c_v = cal[6], t13 = cal[7];
        float bxc = t03 / (-f_u), byc = t13 / (-f_v);
        const float* cr = par + PB_CRN + b * 4;
        float crx0 = cr[0], cry0 = cr[1], crx1 = cr[2], cry1 = cr[3];
        float sx = crx1 - crx0, sy = cry1 - cry0;
        float u1 = bx1 / (float)FW * sx + crx0, v1 = by1 / (float)FH * sy + cry0;
        float u2 = bx2 / (float)FW * sx + crx0, v2 = by2 / (float)FH * sy + cry0;
        float p1x = (u1 - c_u) / f_u + bxc, p1y = (v1 - c_v) / f_v + byc;
        float p2x = (u2 - c_u) / f_u + bxc, p2y = (v2 - c_v) / f_v + byc;
        if (j < 7) cxs[j] = p1x + ((float)j / 6.f) * (p2x - p1x);
        else       cys[j - 7] = p1y + ((float)(j - 7) / 6.f) * (p2y - p1y);
    }
    __syncthreads();

    for (int t = tid; t < CIN * 49; t += 256) {
        int c = t / 49, p = t % 49, oy = p / 7, ox = p % 7;
        long fb = ((long)b * CIN + c) * HW;
        float acc = 0.f;
#pragma unroll
        for (int dy = 0; dy < 2; ++dy) {
            int sy = oy * 2 + dy;
            float ly = lys[sy]; int yA = y0s[sy], yB = y1s[sy], vy = vys[sy];
#pragma unroll
            for (int dx = 0; dx < 2; ++dx) {
                int sx = ox * 2 + dx;
                float lx = lxs[sx]; int xA = x0s[sx], xB = x1s[sx];
                float v = (1.f - ly) * (1.f - lx) * gload(feat, fb + yA * FW + xA, bf)
                        + (1.f - ly) * lx         * gload(feat, fb + yA * FW + xB, bf)
                        + ly * (1.f - lx)         * gload(feat, fb + yB * FW + xA, bf)
                        + ly * lx                 * gload(feat, fb + yB * FW + xB, bf);
                if (!(vy && vxs[sx])) v = 0.f;
                acc += v;
            }
        }
        roi_in[((long)n * CROI + c) * 49 + p] = acc * 0.25f;
    }
    int cls = clsArr[n];
    for (int t = tid; t < 5 * 49; t += 256) {
        int ch = t / 49, p = t % 49, i = p / 7, j = p % 7;
        float v;
        if (ch == 0)      v = cxs[j];
        else if (ch == 1) v = cys[i];
        else              v = (cls == ch - 2) ? 1.f : 0.f;
        roi_in[((long)n * CROI + 64 + ch) * 49 + p] = v;
    }
}

// =====================================================================
// ROI head: conv3x3(69->256,pad1)+b1 -> BN -> relu -> mean -> 1x1
// =====================================================================
__global__ __launch_bounds__(256)
void kHead(const float* __restrict__ roi_in, const float* __restrict__ w1h,
           const float* __restrict__ par, float* __restrict__ head_out) {
    const int h = blockIdx.x, n = blockIdx.y, tid = threadIdx.x;
    const int ocArr[4] = {2, 2, 4, 24};
    const int offArr[4] = {0, 2, 4, 8};
    __shared__ float in_lds[CROI][9][12];
    __shared__ float means[256];

    float* il = &in_lds[0][0][0];
    for (int i = tid; i < CROI * 9 * 12; i += 256) il[i] = 0.f;
    __syncthreads();
    for (int i = tid; i < CROI * 49; i += 256) {
        int c = i / 49, p = i % 49, oy = p / 7, ox = p % 7;
        in_lds[c][oy + 1][ox + 1] = roi_in[((long)n * CROI + c) * 49 + p];
    }
    __syncthreads();

    float acc[49];
#pragma unroll
    for (int p = 0; p < 49; ++p) acc[p] = 0.f;

    const float* wsrc = w1h + (long)h * 158976;
    for (int ci = 0; ci < CROI; ++ci) {
        float wv[9];
#pragma unroll
        for (int j = 0; j < 9; ++j) wv[j] = wsrc[(ci * 9 + j) * 256 + tid];
#pragma unroll
        for (int r = 0; r < 9; ++r) {
            float4 q0 = *(const float4*)&in_lds[ci][r][0];
            float4 q1 = *(const float4*)&in_lds[ci][r][4];
            float4 q2 = *(const float4*)&in_lds[ci][r][8];
            float row[12] = {q0.x, q0.y, q0.z, q0.w, q1.x, q1.y, q1.z, q1.w,
                             q2.x, q2.y, q2.z, q2.w};
#pragma unroll
            for (int ky = 0; ky < 3; ++ky) {
                int oy = r - ky;
                if (oy >= 0 && oy <= 6) {
#pragma unroll
                    for (int ox = 0; ox < 7; ++ox)
#pragma unroll
                        for (int kx = 0; kx < 3; ++kx)
                            acc[oy * 7 + ox] =
                                fmaf(row[ox + kx], wv[ky * 3 + kx], acc[oy * 7 + ox]);
                }
            }
        }
    }

    const float* hb = par + PB_HD0 + h * 7456;
    float b1v = hb[tid], gv = hb[256 + tid], bev = hb[512 + tid];
    float mv = hb[768 + tid], vv = hb[1024 + tid];
    float scale = gv / sqrtf(vv + 1e-5f);
    float s = 0.f;
#pragma unroll
    for (int p = 0; p < 49; ++p)
        s += fmaxf((acc[p] + b1v - mv) * scale + bev, 0.f);
    means[tid] = s / 49.f;
    __syncthreads();
    int oc = ocArr[h];
    if (tid < oc) {
        float o = hb[1280 + oc * 256 + tid];            // b2
        for (int c = 0; c < 256; ++c) o += means[c] * hb[1280 + tid * 256 + c];
        head_out[(long)n * 32 + offArr[h] + tid] = o;
    }
}

// =====================================================================
// Final scalar math + small outputs
// =====================================================================
__global__ void kFinal(const float* __restrict__ head_out, const float* __restrict__ boxes,
                       const int* __restrict__ clsArr, const float* __restrict__ par,
                       void* __restrict__ out, const int* __restrict__ flag) {
    int n = blockIdx.x * 256 + threadIdx.x;
    if (n >= NROI) return;
    const int bf = *flag;
    const float* ho = head_out + (long)n * 32;
    float dep0 = ho[0], dep1 = ho[1];
    int b = (int)boxes[n * 5 + 0];
    int cls = clsArr[n];

    for (int j = 0; j < 24; ++j) gstore(out, O_HEAD + n * 24 + j, ho[8 + j], bf);
    gstore(out, O_OFF3 + n * 2 + 0, ho[2], bf);
    gstore(out, O_OFF3 + n * 2 + 1, ho[3], bf);
    gstore(out, O_S3D + n * 3 + 0, ho[4], bf);
    gstore(out, O_S3D + n * 3 + 1, ho[5], bf);
    gstore(out, O_S3D + n * 3 + 2, ho[6], bf);
    gstore(out, O_H3D + n, ho[7], bf);

    float cry0 = par[PB_CRN + b * 4 + 1], cry1 = par[PB_CRN + b * 4 + 3];
    float sy = cry1 - cry0;
    float bi2 = boxes[n * 5 + 2] / (float)FH * sy + cry0;
    float bi4 = boxes[n * 5 + 4] / (float)FH * sy + cry0;
    float box_h = fmaxf(bi4 - bi2, 1.f);
    float f_u = par[PB_CAL + b * 12 + 0];
    float size3d0 = par[PB_MSZ + cls * 3 + 0] + ho[4];
    float depth_geo = size3d0 / box_h * f_u;
    float sig = 1.f / (1.f + expf(-dep0));
    float d0 = 1.f / (sig + 1e-6f) - 1.f + depth_geo;
    float dgls = ho[7] + 2.f * (logf(f_u) - logf(box_h));
    float mx = fmaxf(dep1, dgls);
    float lse = mx + logf(expf(dep1 - mx) + expf(dgls - mx));
    gstore(out, O_DEP + n * 2 + 0, d0, bf);
    gstore(out, O_DEP + n * 2 + 1, lse, bf);
}

// =====================================================================
extern "C" void kernel_launch(void* const* d_in, const int* in_sizes, int n_in,
                              void* d_out, int out_size, void* d_ws, size_t ws_size,
                              hipStream_t stream) {
    (void)in_sizes; (void)n_in; (void)out_size; (void)ws_size;
    float* ws = (float*)d_ws;
    float* par = ws + WS_PAR;
    int* flag = (int*)(ws + WS_FLAG);
    u16* wb16 = (u16*)(ws + WS_WB16);
    const void* feat = d_in[0];

    kDetect<<<1, 512, 0, stream>>>(feat, flag);

    WPtrs WP;
    WP.bw[0] = d_in[4]; WP.bw[1] = d_in[8]; WP.bw[2] = d_in[12];
    WP.hw[0] = d_in[16]; WP.hw[1] = d_in[24]; WP.hw[2] = d_in[32]; WP.hw[3] = d_in[40];
    kPrepW<<<4788, 256, 0, stream>>>(WP, flag, ws + WS_W1T, wb16, ws + WS_W1H);

    Segs SG; int si = 0;
    auto add = [&](const void* s, int n, int dst) {
        SG.s[si].src = s; SG.s[si].n = n; SG.s[si].dst = dst; ++si;
    };
    add(d_in[1], 96, PB_CAL); add(d_in[2], 32, PB_CRN); add(d_in[3], 9, PB_MSZ);
    const int ocb[3] = {3, 2, 2};
    for (int b = 0; b < 3; ++b) {
        int base = PB_BR0 + b * 1040;
        int i0 = 4 + 4 * b;
        add(d_in[i0 + 1], 256, base);
        add(d_in[i0 + 2], ocb[b] * 256, base + 256);
        add(d_in[i0 + 3], ocb[b], base + 256 + ocb[b] * 256);
    }
    const int och[4] = {2, 2, 4, 24};
    for (int h = 0; h < 4; ++h) {
        int base = PB_HD0 + h * 7456;
        int i0 = 16 + 8 * h;
        add(d_in[i0 + 1], 256, base);
        add(d_in[i0 + 2], 256, base + 256);
        add(d_in[i0 + 3], 256, base + 512);
        add(d_in[i0 + 4], 256, base + 768);
        add(d_in[i0 + 5], 256, base + 1024);
        add(d_in[i0 + 6], och[h] * 256, base + 1280);
        add(d_in[i0 + 7], och[h], base + 1280 + och[h] * 256);
    }
    kPrepP<<<si, 256, 0, stream>>>(SG, flag, par);

    // MFMA branches
    kBranchM<3><<<dim3(5, 96, 8), 256, 0, stream>>>(
        feat, flag, wb16, par + PB_BR0, d_out, O_HEAT, ws + WS_HEAT);
    kBranchM<2><<<dim3(5, 96, 8), 256, 0, stream>>>(
        feat, flag, wb16 + 147456, par + PB_BR0 + 1040, d_out, O_OFF2, ws + WS_OFF2);
    kBranchM<2><<<dim3(5, 96, 8), 256, 0, stream>>>(
        feat, flag, wb16 + 294912, par + PB_BR0 + 2080, d_out, O_SIZ2, ws + WS_SIZ2);

    // exact f32 strip for NMS/topk decision region (rows 0..4 of heat)
    kBranchX<<<dim3(5, 5, 8), 256, 0, stream>>>(
        feat, flag, ws + WS_W1T, par + PB_BR0, d_out, O_HEAT, ws + WS_HEAT);

    kNms<<<2880, 256, 0, stream>>>(ws + WS_HEAT, ws + WS_NH);
    kTop1<<<24, 256, 0, stream>>>(ws + WS_NH, ws + WS_S1S, (int*)(ws + WS_S1I));
    kTop2<<<8, 64, 0, stream>>>(ws + WS_S1S, (int*)(ws + WS_S1I), ws + WS_OFF2,
                                ws + WS_SIZ2, ws + WS_BOX, (int*)(ws + WS_CLS));
    kRoi<<<400, 256, 0, stream>>>(feat, flag, ws + WS_BOX, (int*)(ws + WS_CLS),
                                  par, ws + WS_ROI);
    kHead<<<dim3(4, NROI), 256, 0, stream>>>(ws + WS_ROI, ws + WS_W1H, par, ws + WS_HOUT);
    kFinal<<<2, 256, 0, stream>>>(ws + WS_HOUT, ws + WS_BOX, (int*)(ws + WS_CLS),
                                  par, d_out, flag);
}

// Round 4
// 1532.962 us; speedup vs baseline: 2.5813x; 1.3665x over previous
//
#include <hip/hip_runtime.h>
#include <math.h>

typedef unsigned short u16;
typedef unsigned int   u32;
typedef unsigned long long u64;
typedef __attribute__((ext_vector_type(8))) short short8;   // 8 bf16 (4 VGPR)
typedef __attribute__((ext_vector_type(4))) float f32x4;    // MFMA acc

// ---------- dtype helpers ----------
__device__ __forceinline__ float b2f(u16 v) { return __uint_as_float(((u32)v) << 16); }
__device__ __forceinline__ u16 f2b(float f) {
    u32 u = __float_as_uint(f);
    u32 r = (u + 0x7FFFu + ((u >> 16) & 1u)) >> 16;   // RNE
    return (u16)r;
}
__device__ __forceinline__ float gload(const void* p, long i, int bf) {
    return bf ? b2f(((const u16*)p)[i]) : ((const float*)p)[i];
}
__device__ __forceinline__ void gstore(void* p, long i, float v, int bf) {
    if (bf) ((u16*)p)[i] = f2b(v);
    else    ((float*)p)[i] = v;
}

// top-k key: smallest key = (largest value, then smallest index)
__device__ __forceinline__ u64 packKey(float v, int idx) {
    u32 u = __float_as_uint(v);
    u32 m = (u & 0x80000000u) ? ~u : (u | 0x80000000u);   // monotone float->uint
    return ((u64)(~m) << 32) | (u32)idx;
}

// ---------- problem constants ----------
#define BATCH 8
#define CIN   64
#define FH    96
#define FW    320
#define KDET  50
#define NROI  400
#define CROI  69
#define HW    (FH*FW)
#define CHUNK 1920
#define NCHUNK 16

// ---------- workspace layout (float offsets) ----------
#define WS_HEAT 0L
#define WS_OFF2 737280L
#define WS_SIZ2 1228800L
#define WS_NH   1720320L
#define WS_S1S  2457600L
#define WS_S1I  2458800L
#define WS_CLS  2460000L
#define WS_BOX  2460400L
#define WS_ROI  2462400L
#define WS_HOUT 3814800L
#define WS_W1T  3827600L     // 147456 f32: hm conv1 [k=576][c=256] (exact strip)
#define WS_WB16 3975056L     // u16: 3 branches * [9][256][64] bf16
#define WS_W1H  4269968L     // 4 * 621*256 f32 (head conv1, [k][c])
#define WS_PAR  4905872L     // packed f32 params
#define WS_FLAG 4938960L     // int dtype flag

// param block sub-offsets
#define PB_CAL 0
#define PB_CRN 96
#define PB_MSZ 128
#define PB_BR0 144          // stride 1040: b1@0, w2@256 ([k][n]), b2@256+OC*256
#define PB_HD0 3264         // stride 7456

// ---------- output layout (element offsets) ----------
#define O_HEAT 0L
#define O_OFF2 737280L
#define O_SIZ2 1228800L
#define O_HEAD 1720320L
#define O_DEP  1729920L
#define O_OFF3 1730720L
#define O_S3D  1731520L
#define O_H3D  1732720L

// =====================================================================
// dtype detection
// =====================================================================
__global__ void kDetect(const void* __restrict__ feat, int* __restrict__ flag) {
    __shared__ int cnt;
    if (threadIdx.x == 0) cnt = 0;
    __syncthreads();
    u16 v = ((const u16*)feat)[threadIdx.x];     // 512 threads
    float f = b2f(v);
    u32 e = (v >> 7) & 0xFF;
    float a = fabsf(f);
    int sane = (e != 0xFF) && (f == 0.f || (a >= 1e-8f && a <= 1e4f));
    atomicAdd(&cnt, sane);
    __syncthreads();
    if (threadIdx.x == 0) *flag = (cnt >= 480) ? 1 : 0;
}

// =====================================================================
// Prep: weights
// =====================================================================
struct WPtrs { const void* bw[3]; const void* hw[4]; };

__global__ void kPrepW(WPtrs P, const int* __restrict__ flag,
                       float* __restrict__ w1t, u16* __restrict__ wb16,
                       float* __restrict__ w1h) {
    const int bf = *flag;
    int idx = blockIdx.x * 256 + threadIdx.x;
    if (idx < 147456) {
        int k = idx >> 8, c = idx & 255;
        w1t[idx] = gload(P.bw[0], (long)c * 576 + k, bf);
    } else if (idx < 147456 + 442368) {
        int j = idx - 147456;
        int br = j / 147456, rem = j % 147456;
        int tap = rem / 16384, n = (rem >> 6) & 255, ci = rem & 63;
        wb16[j] = f2b(gload(P.bw[br], (long)n * 576 + ci * 9 + tap, bf));
    } else {
        int j = idx - 147456 - 442368;
        if (j < 4 * 158976) {
            int h = j / 158976, rem = j % 158976;
            int k = rem >> 8, c = rem & 255;
            w1h[j] = gload(P.hw[h], (long)c * 621 + k, bf);
        }
    }
}

// Prep: pack all small params to f32
struct Seg { const void* src; int n; int dst; };
struct Segs { Seg s[40]; };

__global__ void kPrepP(Segs S, const int* __restrict__ flag, float* __restrict__ par) {
    const int bf = *flag;
    Seg sg = S.s[blockIdx.x];
    for (int i = threadIdx.x; i < sg.n; i += 256)
        par[sg.dst + i] = gload(sg.src, i, bf);
}

// =====================================================================
// MFMA branch: conv3x3(64->256) as 9 shifted GEMMs + b1 + ReLU + 1x1 + b2
// =====================================================================
template<int OC>
__global__ __launch_bounds__(256, 2)
void kBranchM(const void* __restrict__ feat, const int* __restrict__ flag,
              const u16* __restrict__ wb,     // [9][256][64] bf16
              const float* __restrict__ bp,   // b1, w2[k][n], b2
              void* __restrict__ outb, long obase, float* __restrict__ outf) {
    __shared__ __align__(16) u16 a_lds[3][68][72];
    __shared__ __align__(16) u16 w_lds[256][72];
    __shared__ float red[4][64][OC];

    const int bfl = *flag;
    const int tid = threadIdx.x;
    const int wave = tid >> 6, lane = tid & 63;
    const int q = lane >> 4, n15 = lane & 15;
    const int x0 = blockIdx.x * 64, y = blockIdx.y, b = blockIdx.z;
    const int n0 = wave * 64;

    if (tid < 192) {
        const int ci = tid & 63, r = tid >> 6;
        const int gy = y - 1 + r;
        if (gy < 0 || gy >= FH) {
            for (int xi = 0; xi < 66; ++xi) a_lds[r][xi][ci] = 0;
        } else if (bfl) {
            const u16* rp = (const u16*)feat + ((long)((b << 6) | ci) * FH + gy) * FW;
            for (int j = 0; j < 10; ++j) {
                int xs0 = x0 - 8 + j * 8;
                u16 tmp[8];
                if (xs0 >= 0 && xs0 <= FW - 8)
                    *(uint4*)tmp = *(const uint4*)(rp + xs0);
                else
                    for (int e = 0; e < 8; ++e) {
                        int gx = xs0 + e;
                        tmp[e] = (gx >= 0 && gx < FW) ? rp[gx] : (u16)0;
                    }
                for (int e = 0; e < 8; ++e) {
                    int xi = xs0 + e - x0 + 1;
                    if (xi >= 0 && xi < 66) a_lds[r][xi][ci] = tmp[e];
                }
            }
        } else {
            const float* rp = (const float*)feat + ((long)((b << 6) | ci) * FH + gy) * FW;
            for (int j = 0; j < 18; ++j) {
                int xs0 = x0 - 4 + j * 4;
                float tmp[4];
                if (xs0 >= 0 && xs0 <= FW - 4)
                    *(float4*)tmp = *(const float4*)(rp + xs0);
                else
                    for (int e = 0; e < 4; ++e) {
                        int gx = xs0 + e;
                        tmp[e] = (gx >= 0 && gx < FW) ? rp[gx] : 0.f;
                    }
                for (int e = 0; e < 4; ++e) {
                    int xi = xs0 + e - x0 + 1;
                    if (xi >= 0 && xi < 66) a_lds[r][xi][ci] = f2b(tmp[e]);
                }
            }
        }
    }

    f32x4 acc[4][4];
#pragma unroll
    for (int i = 0; i < 4; ++i)
#pragma unroll
        for (int t = 0; t < 4; ++t) acc[i][t] = (f32x4){0.f, 0.f, 0.f, 0.f};

    for (int tap = 0; tap < 9; ++tap) {
        __syncthreads();
        const u16* wt = wb + tap * 16384;
        for (int i = tid; i < 2048; i += 256) {
            int n = i >> 3, c8 = i & 7;
            *(uint4*)&w_lds[n][c8 * 8] = *(const uint4*)(wt + n * 64 + c8 * 8);
        }
        __syncthreads();
        const int ky = tap / 3, kx = tap % 3;
#pragma unroll
        for (int s = 0; s < 2; ++s) {
            short8 afr[4], bfr[4];
#pragma unroll
            for (int i = 0; i < 4; ++i)
                afr[i] = *(const short8*)&a_lds[ky][i * 16 + n15 + kx][s * 32 + q * 8];
#pragma unroll
            for (int t = 0; t < 4; ++t)
                bfr[t] = *(const short8*)&w_lds[n0 + t * 16 + n15][s * 32 + q * 8];
#pragma unroll
            for (int i = 0; i < 4; ++i)
#pragma unroll
                for (int t = 0; t < 4; ++t)
                    acc[i][t] = __builtin_amdgcn_mfma_f32_16x16x32_bf16(
                        afr[i], bfr[t], acc[i][t], 0, 0, 0);
        }
    }

    float b1v[4], w2v[OC][4];
#pragma unroll
    for (int t = 0; t < 4; ++t) {
        int n = n0 + t * 16 + n15;
        b1v[t] = bp[n];
#pragma unroll
        for (int k = 0; k < OC; ++k) w2v[k][t] = bp[256 + k * 256 + n];
    }
#pragma unroll
    for (int i = 0; i < 4; ++i) {
#pragma unroll
        for (int r = 0; r < 4; ++r) {
            float pk[OC];
#pragma unroll
            for (int k = 0; k < OC; ++k) pk[k] = 0.f;
#pragma unroll
            for (int t = 0; t < 4; ++t) {
                float h = fmaxf(acc[i][t][r] + b1v[t], 0.f);
#pragma unroll
                for (int k = 0; k < OC; ++k) pk[k] = fmaf(h, w2v[k][t], pk[k]);
            }
#pragma unroll
            for (int k = 0; k < OC; ++k) {
                pk[k] += __shfl_xor(pk[k], 1);
                pk[k] += __shfl_xor(pk[k], 2);
                pk[k] += __shfl_xor(pk[k], 4);
                pk[k] += __shfl_xor(pk[k], 8);
            }
            if (n15 == 0) {
#pragma unroll
                for (int k = 0; k < OC; ++k)
                    red[wave][i * 16 + q * 4 + r][k] = pk[k];
            }
        }
    }
    __syncthreads();
    if (tid < 64 * OC) {
        int k = tid >> 6, px = tid & 63;
        float s = bp[256 + OC * 256 + k];
#pragma unroll
        for (int w = 0; w < 4; ++w) s += red[w][px][k];
        long o = (((long)b * OC + k) * FH + y) * FW + x0 + px;
        gstore(outb, obase + o, s, bfl);
        outf[o] = s;
    }
}

// =====================================================================
// Exact f32 strip (rows 0..4 of heat): NMS/topk decisions bit-match f32
// =====================================================================
union BrLds {
    float w[36 * 256];
    float part[32 * 3 * 64];
};

__global__ __launch_bounds__(256)
void kBranchX(const void* __restrict__ feat, const int* __restrict__ flag,
              const float* __restrict__ w1t, const float* __restrict__ bp,
              void* __restrict__ outb, long obase, float* __restrict__ outf) {
    __shared__ float in_lds[4][3][68];
    __shared__ BrLds u;
    const int bf = *flag;
    const int OC = 3;

    const int tid = threadIdx.x;
    const int xg = tid & 7, cg = tid >> 3;
    const int x0 = blockIdx.x * 64, y = blockIdx.y, b = blockIdx.z;
    const int c0 = cg * 8;

    float acc[8][8];
#pragma unroll
    for (int i = 0; i < 8; ++i)
#pragma unroll
        for (int j = 0; j < 8; ++j) acc[i][j] = 0.f;

    for (int chunk = 0; chunk < 16; ++chunk) {
        const int ci0 = chunk * 4;
        __syncthreads();
        for (int i = tid; i < 4 * 3 * 68; i += 256) {
            int xx = i % 68, t2 = i / 68;
            int r = t2 % 3, ci = t2 / 3;
            int gx = x0 - 1 + xx, gy = y - 1 + r;
            float v = 0.f;
            if (gx >= 0 && gx < FW && gy >= 0 && gy < FH)
                v = gload(feat, ((long)(b * CIN + ci0 + ci) * FH + gy) * FW + gx, bf);
            in_lds[ci][r][xx] = v;
        }
        {
            const float4* src = (const float4*)(w1t + (long)ci0 * 9 * 256);
            float4* dst = (float4*)u.w;
            for (int i = tid; i < 36 * 256 / 4; i += 256) dst[i] = src[i];
        }
        __syncthreads();
#pragma unroll
        for (int ci = 0; ci < 4; ++ci) {
#pragma unroll
            for (int ky = 0; ky < 3; ++ky) {
                const float* rowp = &in_lds[ci][ky][xg * 8];
                float inv[10];
                *(float4*)&inv[0] = *(const float4*)&rowp[0];
                *(float4*)&inv[4] = *(const float4*)&rowp[4];
                *(float2*)&inv[8] = *(const float2*)&rowp[8];
#pragma unroll
                for (int kx = 0; kx < 3; ++kx) {
                    const float* wp = &u.w[(ci * 9 + ky * 3 + kx) * 256 + c0];
                    float wv[8];
                    *(float4*)&wv[0] = *(const float4*)&wp[0];
                    *(float4*)&wv[4] = *(const float4*)&wp[4];
#pragma unroll
                    for (int cc = 0; cc < 8; ++cc)
#pragma unroll
                        for (int xx = 0; xx < 8; ++xx)
                            acc[cc][xx] = fmaf(wv[cc], inv[xx + kx], acc[cc][xx]);
                }
            }
        }
    }

#pragma unroll
    for (int cc = 0; cc < 8; ++cc) {
        float b1v = bp[c0 + cc];
#pragma unroll
        for (int xx = 0; xx < 8; ++xx)
            acc[cc][xx] = fmaxf(acc[cc][xx] + b1v, 0.f);
    }

    __syncthreads();
#pragma unroll
    for (int k = 0; k < OC; ++k) {
        float p[8];
#pragma unroll
        for (int xx = 0; xx < 8; ++xx) p[xx] = 0.f;
#pragma unroll
        for (int cc = 0; cc < 8; ++cc) {
            float wv = bp[256 + k * 256 + c0 + cc];
#pragma unroll
            for (int xx = 0; xx < 8; ++xx) p[xx] = fmaf(acc[cc][xx], wv, p[xx]);
        }
#pragma unroll
        for (int xx = 0; xx < 8; ++xx)
            u.part[(cg * OC + k) * 64 + xg * 8 + xx] = p[xx];
    }
    __syncthreads();
    for (int t = tid; t < OC * 64; t += 256) {
        int k = t >> 6, xx = t & 63;
        float s = bp[256 + OC * 256 + k];
#pragma unroll 8
        for (int g = 0; g < 32; ++g) s += u.part[(g * OC + k) * 64 + xx];
        long o = (((long)b * OC + k) * FH + y) * FW + x0 + xx;
        gstore(outb, obase + o, s, bf);
        outf[o] = s;
    }
}

// =====================================================================
// NMS
// =====================================================================
__global__ void kNms(const float* __restrict__ heat, float* __restrict__ nh) {
    int idx = blockIdx.x * 256 + threadIdx.x;
    if (idx >= 737280) return;
    int x = idx % FW, t = idx / FW;
    int yy = t % FH, bc = t / FH;
    const float* p = heat + (long)bc * HW;
    float v = p[yy * FW + x];
    float m = v;
    for (int dy = -1; dy <= 1; ++dy) {
        int ny = yy + dy;
        if (ny < 0 || ny >= FH) continue;
        for (int dx = -1; dx <= 1; ++dx) {
            int nx = x + dx;
            if (nx < 0 || nx >= FW) continue;
            m = fmaxf(m, p[ny * FW + nx]);
        }
    }
    nh[idx] = (v == m) ? v : 0.f;
}

// =====================================================================
// top-k stage A: per (bc, chunk) local top-50 via single-wave extraction.
// Writes 50 u64 keys in-place into the chunk's own nh slice.
// =====================================================================
__global__ __launch_bounds__(256)
void kTopA(float* __restrict__ nh) {
    __shared__ u64 keys[CHUNK];
    const int bc = blockIdx.x, ch = blockIdx.y;
    const int tid = threadIdx.x;
    const long base = (long)bc * HW + (long)ch * CHUNK;
    for (int i = tid; i < CHUNK; i += 256)
        keys[i] = packKey(nh[base + i], ch * CHUNK + i);
    __syncthreads();
    if (tid < 64) {
        const int lane = tid;
        u64* outp = (u64*)(nh + base);
        for (int it = 0; it < KDET; ++it) {
            u64 bk = ~0ULL; int bp = 0;
            for (int i = lane; i < CHUNK; i += 64) {
                u64 k = keys[i];
                if (k < bk) { bk = k; bp = i; }
            }
#pragma unroll
            for (int s = 32; s > 0; s >>= 1) {
                u64 k2 = __shfl_down(bk, s);
                int p2 = __shfl_down(bp, s);
                if (k2 < bk) { bk = k2; bp = p2; }
            }
            bk = __shfl(bk, 0);
            bp = __shfl(bp, 0);
            if (lane == 0) {
                outp[it] = bk;
                keys[bp] = ~0ULL;
            }
        }
    }
}

// =====================================================================
// top-k stage B: merge 16x50 chunk keys -> sorted per-(b,c) top-50
// =====================================================================
__global__ __launch_bounds__(64)
void kTopB(const float* __restrict__ nh, float* __restrict__ s1s,
           int* __restrict__ s1i) {
    __shared__ u64 keys[NCHUNK * KDET];
    const int bc = blockIdx.x, lane = threadIdx.x;
    for (int ch = 0; ch < NCHUNK; ++ch) {
        const u64* src = (const u64*)(nh + (long)bc * HW + (long)ch * CHUNK);
        if (lane < KDET) keys[ch * KDET + lane] = src[lane];
    }
    __syncthreads();
    for (int it = 0; it < KDET; ++it) {
        u64 bk = ~0ULL; int bp = 0;
        for (int i = lane; i < NCHUNK * KDET; i += 64) {
            u64 k = keys[i];
            if (k < bk) { bk = k; bp = i; }
        }
#pragma unroll
        for (int s = 32; s > 0; s >>= 1) {
            u64 k2 = __shfl_down(bk, s);
            int p2 = __shfl_down(bp, s);
            if (k2 < bk) { bk = k2; bp = p2; }
        }
        bk = __shfl(bk, 0);
        bp = __shfl(bp, 0);
        if (lane == 0) {
            u32 hm = ~(u32)(bk >> 32);
            u32 u = (hm & 0x80000000u) ? (hm & 0x7fffffffu) : ~hm;
            s1s[bc * KDET + it] = __uint_as_float(u);
            s1i[bc * KDET + it] = (int)(bk & 0xFFFFFFFFu);
            keys[bp] = ~0ULL;
        }
    }
}

// =====================================================================
// top-50 stage 2 + boxes
// =====================================================================
__global__ void kTop2(const float* __restrict__ s1s, const int* __restrict__ s1i,
                      const float* __restrict__ off2, const float* __restrict__ siz2,
                      float* __restrict__ boxes, int* __restrict__ clsArr) {
    const int b = blockIdx.x, t = threadIdx.x;    // 64 threads
    __shared__ float sc[150];
    for (int i = t; i < 150; i += 64) sc[i] = s1s[b * 150 + i];
    __syncthreads();
    for (int r = 0; r < KDET; ++r) {
        float bv = -INFINITY; int bp = 0x7fffffff;
        for (int i = t; i < 150; i += 64) {
            float v = sc[i];
            if (v > bv) { bv = v; bp = i; }
        }
        for (int s = 32; s > 0; s >>= 1) {
            float v2 = __shfl_down(bv, s);
            int   p2 = __shfl_down(bp, s);
            if (v2 > bv || (v2 == bv && p2 < bp)) { bv = v2; bp = p2; }
        }
        if (t == 0) {
            int cls = bp / KDET;
            int ind = s1i[b * 150 + bp];
            int n = b * KDET + r;
            clsArr[n] = cls;
            int x = ind % FW, yy = ind / FW;
            float cx = (float)x  + off2[(((long)b * 2 + 0) * FH + yy) * FW + x];
            float cy = (float)yy + off2[(((long)b * 2 + 1) * FH + yy) * FW + x];
            float w  = siz2[(((long)b * 2 + 0) * FH + yy) * FW + x];
            float h  = siz2[(((long)b * 2 + 1) * FH + yy) * FW + x];
            boxes[n * 5 + 0] = (float)b;
            boxes[n * 5 + 1] = cx - w * 0.5f;
            boxes[n * 5 + 2] = cy - h * 0.5f;
            boxes[n * 5 + 3] = cx + w * 0.5f;
            boxes[n * 5 + 4] = cy + h * 0.5f;
            sc[bp] = -INFINITY;
        }
        __syncthreads();
    }
}

// =====================================================================
// ROI align 7x7 (sr=2) + coord maps + one-hot -> roi_in f32
// =====================================================================
__global__ __launch_bounds__(256)
void kRoi(const void* __restrict__ feat, const int* __restrict__ flag,
          const float* __restrict__ boxes, const int* __restrict__ clsArr,
          const float* __restrict__ par, float* __restrict__ roi_in) {
    const int n = blockIdx.x, tid = threadIdx.x;
    const int bf = *flag;
    __shared__ int   x0s[14], x1s[14], y0s[14], y1s[14], vxs[14], vys[14];
    __shared__ float lxs[14], lys[14], cxs[7], cys[7];

    const float bx1 = boxes[n * 5 + 1], by1 = boxes[n * 5 + 2];
    const float bx2 = boxes[n * 5 + 3], by2 = boxes[n * 5 + 4];
    const int b = (int)boxes[n * 5 + 0];

    if (tid < 14) {
        float roi_w = fmaxf(bx2 - bx1, 1.f);
        float X = bx1 + (roi_w / 7.f) * ((tid + 0.5f) * 0.5f);
        vxs[tid] = (X > -1.f) && (X < (float)FW);
        float Xc = fminf(fmaxf(X, 0.f), (float)(FW - 1));
        int xi = (int)floorf(Xc);
        x0s[tid] = xi; x1s[tid] = min(xi + 1, FW - 1); lxs[tid] = Xc - (float)xi;
    } else if (tid >= 16 && tid < 30) {
        int i = tid - 16;
        float roi_h = fmaxf(by2 - by1, 1.f);
        float Y = by1 + (roi_h / 7.f) * ((i + 0.5f) * 0.5f);
        vys[i] = (Y > -1.f) && (Y < (float)FH);
        float Yc = fminf(fmaxf(Y, 0.f), (float)(FH - 1));
        int yi = (int)floorf(Yc);
        y0s[i] = yi; y1s[i] = min(yi + 1, FH - 1); lys[i] = Yc - (float)yi;
    } else if (tid >= 32 && tid < 46) {
        int j = tid - 32;
        const float* cal = par + PB_CAL + b * 12;
        float f_u = cal[0], c_u = cal[2], t03 = cal[3];
        float f_v = cal[5], c_v = cal[6], t13 = cal[7];
        float bxc = t03 / (-f_u), byc = t13 / (-f_v);
        const float* cr = par + PB_CRN + b * 4;
        float crx0 = cr[0], cry0 = cr[1], crx1 = cr[2], cry1 = cr[3];
        float sx = crx1 - crx0, sy = cry1 - cry0;
        float u1 = bx1 / (float)FW * sx + crx0, v1 = by1 / (float)FH * sy + cry0;
        float u2 = bx2 / (float)FW * sx + crx0, v2 = by2 / (float)FH * sy + cry0;
        float p1x = (u1 - c_u) / f_u + bxc, p1y = (v1 - c_v) / f_v + byc;
        float p2x = (u2 - c_u) / f_u + bxc, p2y = (v2 - c_v) / f_v + byc;
        if (j < 7) cxs[j] = p1x + ((float)j / 6.f) * (p2x - p1x);
        else       cys[j - 7] = p1y + ((float)(j - 7) / 6.f) * (p2y - p1y);
    }
    __syncthreads();

    for (int t = tid; t < CIN * 49; t += 256) {
        int c = t / 49, p = t % 49, oy = p / 7, ox = p % 7;
        long fb = ((long)b * CIN + c) * HW;
        float acc = 0.f;
#pragma unroll
        for (int dy = 0; dy < 2; ++dy) {
            int sy = oy * 2 + dy;
            float ly = lys[sy]; int yA = y0s[sy], yB = y1s[sy], vy = vys[sy];
#pragma unroll
            for (int dx = 0; dx < 2; ++dx) {
                int sx = ox * 2 + dx;
                float lx = lxs[sx]; int xA = x0s[sx], xB = x1s[sx];
                float v = (1.f - ly) * (1.f - lx) * gload(feat, fb + yA * FW + xA, bf)
                        + (1.f - ly) * lx         * gload(feat, fb + yA * FW + xB, bf)
                        + ly * (1.f - lx)         * gload(feat, fb + yB * FW + xA, bf)
                        + ly * lx                 * gload(feat, fb + yB * FW + xB, bf);
                if (!(vy && vxs[sx])) v = 0.f;
                acc += v;
            }
        }
        roi_in[((long)n * CROI + c) * 49 + p] = acc * 0.25f;
    }
    int cls = clsArr[n];
    for (int t = tid; t < 5 * 49; t += 256) {
        int ch = t / 49, p = t % 49, i = p / 7, j = p % 7;
        float v;
        if (ch == 0)      v = cxs[j];
        else if (ch == 1) v = cys[i];
        else              v = (cls == ch - 2) ? 1.f : 0.f;
        roi_in[((long)n * CROI + 64 + ch) * 49 + p] = v;
    }
}

// =====================================================================
// ROI head: conv3x3(69->256,pad1)+b1 -> BN -> relu -> mean -> 1x1
// =====================================================================
__global__ __launch_bounds__(256)
void kHead(const float* __restrict__ roi_in, const float* __restrict__ w1h,
           const float* __restrict__ par, float* __restrict__ head_out) {
    const int h = blockIdx.x, n = blockIdx.y, tid = threadIdx.x;
    const int ocArr[4] = {2, 2, 4, 24};
    const int offArr[4] = {0, 2, 4, 8};
    __shared__ float in_lds[CROI][9][12];
    __shared__ float means[256];

    float* il = &in_lds[0][0][0];
    for (int i = tid; i < CROI * 9 * 12; i += 256) il[i] = 0.f;
    __syncthreads();
    for (int i = tid; i < CROI * 49; i += 256) {
        int c = i / 49, p = i % 49, oy = p / 7, ox = p % 7;
        in_lds[c][oy + 1][ox + 1] = roi_in[((long)n * CROI + c) * 49 + p];
    }
    __syncthreads();

    float acc[49];
#pragma unroll
    for (int p = 0; p < 49; ++p) acc[p] = 0.f;

    const float* wsrc = w1h + (long)h * 158976;
    for (int ci = 0; ci < CROI; ++ci) {
        float wv[9];
#pragma unroll
        for (int j = 0; j < 9; ++j) wv[j] = wsrc[(ci * 9 + j) * 256 + tid];
#pragma unroll
        for (int r = 0; r < 9; ++r) {
            float4 q0 = *(const float4*)&in_lds[ci][r][0];
            float4 q1 = *(const float4*)&in_lds[ci][r][4];
            float4 q2 = *(const float4*)&in_lds[ci][r][8];
            float row[12] = {q0.x, q0.y, q0.z, q0.w, q1.x, q1.y, q1.z, q1.w,
                             q2.x, q2.y, q2.z, q2.w};
#pragma unroll
            for (int ky = 0; ky < 3; ++ky) {
                int oy = r - ky;
                if (oy >= 0 && oy <= 6) {
#pragma unroll
                    for (int ox = 0; ox < 7; ++ox)
#pragma unroll
                        for (int kx = 0; kx < 3; ++kx)
                            acc[oy * 7 + ox] =
                                fmaf(row[ox + kx], wv[ky * 3 + kx], acc[oy * 7 + ox]);
                }
            }
        }
    }

    const float* hb = par + PB_HD0 + h * 7456;
    float b1v = hb[tid], gv = hb[256 + tid], bev = hb[512 + tid];
    float mv = hb[768 + tid], vv = hb[1024 + tid];
    float scale = gv / sqrtf(vv + 1e-5f);
    float s = 0.f;
#pragma unroll
    for (int p = 0; p < 49; ++p)
        s += fmaxf((acc[p] + b1v - mv) * scale + bev, 0.f);
    means[tid] = s / 49.f;
    __syncthreads();
    int oc = ocArr[h];
    if (tid < oc) {
        float o = hb[1280 + oc * 256 + tid];            // b2
        for (int c = 0; c < 256; ++c) o += means[c] * hb[1280 + tid * 256 + c];
        head_out[(long)n * 32 + offArr[h] + tid] = o;
    }
}

// =====================================================================
// Final scalar math + small outputs
// =====================================================================
__global__ void kFinal(const float* __restrict__ head_out, const float* __restrict__ boxes,
                       const int* __restrict__ clsArr, const float* __restrict__ par,
                       void* __restrict__ out, const int* __restrict__ flag) {
    int n = blockIdx.x * 256 + threadIdx.x;
    if (n >= NROI) return;
    const int bf = *flag;
    const float* ho = head_out + (long)n * 32;
    float dep0 = ho[0], dep1 = ho[1];
    int b = (int)boxes[n * 5 + 0];
    int cls = clsArr[n];

    for (int j = 0; j < 24; ++j) gstore(out, O_HEAD + n * 24 + j, ho[8 + j], bf);
    gstore(out, O_OFF3 + n * 2 + 0, ho[2], bf);
    gstore(out, O_OFF3 + n * 2 + 1, ho[3], bf);
    gstore(out, O_S3D + n * 3 + 0, ho[4], bf);
    gstore(out, O_S3D + n * 3 + 1, ho[5], bf);
    gstore(out, O_S3D + n * 3 + 2, ho[6], bf);
    gstore(out, O_H3D + n, ho[7], bf);

    float cry0 = par[PB_CRN + b * 4 + 1], cry1 = par[PB_CRN + b * 4 + 3];
    float sy = cry1 - cry0;
    float bi2 = boxes[n * 5 + 2] / (float)FH * sy + cry0;
    float bi4 = boxes[n * 5 + 4] / (float)FH * sy + cry0;
    float box_h = fmaxf(bi4 - bi2, 1.f);
    float f_u = par[PB_CAL + b * 12 + 0];
    float size3d0 = par[PB_MSZ + cls * 3 + 0] + ho[4];
    float depth_geo = size3d0 / box_h * f_u;
    float sig = 1.f / (1.f + expf(-dep0));
    float d0 = 1.f / (sig + 1e-6f) - 1.f + depth_geo;
    float dgls = ho[7] + 2.f * (logf(f_u) - logf(box_h));
    float mx = fmaxf(dep1, dgls);
    float lse = mx + logf(expf(dep1 - mx) + expf(dgls - mx));
    gstore(out, O_DEP + n * 2 + 0, d0, bf);
    gstore(out, O_DEP + n * 2 + 1, lse, bf);
}

// =====================================================================
extern "C" void kernel_launch(void* const* d_in, const int* in_sizes, int n_in,
                              void* d_out, int out_size, void* d_ws, size_t ws_size,
                              hipStream_t stream) {
    (void)in_sizes; (void)n_in; (void)out_size; (void)ws_size;
    float* ws = (float*)d_ws;
    float* par = ws + WS_PAR;
    int* flag = (int*)(ws + WS_FLAG);
    u16* wb16 = (u16*)(ws + WS_WB16);
    const void* feat = d_in[0];

    kDetect<<<1, 512, 0, stream>>>(feat, flag);

    WPtrs WP;
    WP.bw[0] = d_in[4]; WP.bw[1] = d_in[8]; WP.bw[2] = d_in[12];
    WP.hw[0] = d_in[16]; WP.hw[1] = d_in[24]; WP.hw[2] = d_in[32]; WP.hw[3] = d_in[40];
    kPrepW<<<4788, 256, 0, stream>>>(WP, flag, ws + WS_W1T, wb16, ws + WS_W1H);

    Segs SG; int si = 0;
    auto add = [&](const void* s, int n, int dst) {
        SG.s[si].src = s; SG.s[si].n = n; SG.s[si].dst = dst; ++si;
    };
    add(d_in[1], 96, PB_CAL); add(d_in[2], 32, PB_CRN); add(d_in[3], 9, PB_MSZ);
    const int ocb[3] = {3, 2, 2};
    for (int b = 0; b < 3; ++b) {
        int base = PB_BR0 + b * 1040;
        int i0 = 4 + 4 * b;
        add(d_in[i0 + 1], 256, base);
        add(d_in[i0 + 2], ocb[b] * 256, base + 256);
        add(d_in[i0 + 3], ocb[b], base + 256 + ocb[b] * 256);
    }
    const int och[4] = {2, 2, 4, 24};
    for (int h = 0; h < 4; ++h) {
        int base = PB_HD0 + h * 7456;
        int i0 = 16 + 8 * h;
        add(d_in[i0 + 1], 256, base);
        add(d_in[i0 + 2], 256, base + 256);
        add(d_in[i0 + 3], 256, base + 512);
        add(d_in[i0 + 4], 256, base + 768);
        add(d_in[i0 + 5], 256, base + 1024);
        add(d_in[i0 + 6], och[h] * 256, base + 1280);
        add(d_in[i0 + 7], och[h], base + 1280 + och[h] * 256);
    }
    kPrepP<<<si, 256, 0, stream>>>(SG, flag, par);

    // MFMA branches
    kBranchM<3><<<dim3(5, 96, 8), 256, 0, stream>>>(
        feat, flag, wb16, par + PB_BR0, d_out, O_HEAT, ws + WS_HEAT);
    kBranchM<2><<<dim3(5, 96, 8), 256, 0, stream>>>(
        feat, flag, wb16 + 147456, par + PB_BR0 + 1040, d_out, O_OFF2, ws + WS_OFF2);
    kBranchM<2><<<dim3(5, 96, 8), 256, 0, stream>>>(
        feat, flag, wb16 + 294912, par + PB_BR0 + 2080, d_out, O_SIZ2, ws + WS_SIZ2);

    // exact f32 strip for NMS/topk decision region (rows 0..4 of heat)
    kBranchX<<<dim3(5, 5, 8), 256, 0, stream>>>(
        feat, flag, ws + WS_W1T, par + PB_BR0, d_out, O_HEAT, ws + WS_HEAT);

    kNms<<<2880, 256, 0, stream>>>(ws + WS_HEAT, ws + WS_NH);
    kTopA<<<dim3(24, NCHUNK), 256, 0, stream>>>(ws + WS_NH);
    kTopB<<<24, 64, 0, stream>>>(ws + WS_NH, ws + WS_S1S, (int*)(ws + WS_S1I));
    kTop2<<<8, 64, 0, stream>>>(ws + WS_S1S, (int*)(ws + WS_S1I), ws + WS_OFF2,
                                ws + WS_SIZ2, ws + WS_BOX, (int*)(ws + WS_CLS));
    kRoi<<<400, 256, 0, stream>>>(feat, flag, ws + WS_BOX, (int*)(ws + WS_CLS),
                                  par, ws + WS_ROI);
    kHead<<<dim3(4, NROI), 256, 0, stream>>>(ws + WS_ROI, ws + WS_W1H, par, ws + WS_HOUT);
    kFinal<<<2, 256, 0, stream>>>(ws + WS_HOUT, ws + WS_BOX, (int*)(ws + WS_CLS),
                                  par, d_out, flag);
}

// Round 5
// 1361.228 us; speedup vs baseline: 2.9069x; 1.1262x over previous
//
#include <hip/hip_runtime.h>
#include <math.h>

typedef unsigned short u16;
typedef unsigned int   u32;
typedef unsigned long long u64;
typedef __attribute__((ext_vector_type(8))) short short8;   // 8 bf16 (4 VGPR)
typedef __attribute__((ext_vector_type(4))) float f32x4;    // MFMA acc

// ---------- dtype helpers ----------
__device__ __forceinline__ float b2f(u16 v) { return __uint_as_float(((u32)v) << 16); }
__device__ __forceinline__ u16 f2b(float f) {
    u32 u = __float_as_uint(f);
    u32 r = (u + 0x7FFFu + ((u >> 16) & 1u)) >> 16;   // RNE
    return (u16)r;
}
__device__ __forceinline__ float gload(const void* p, long i, int bf) {
    return bf ? b2f(((const u16*)p)[i]) : ((const float*)p)[i];
}
__device__ __forceinline__ void gstore(void* p, long i, float v, int bf) {
    if (bf) ((u16*)p)[i] = f2b(v);
    else    ((float*)p)[i] = v;
}

// top-k key: smallest key = (largest value, then smallest index)
__device__ __forceinline__ u64 packKey(float v, int idx) {
    u32 u = __float_as_uint(v);
    u32 m = (u & 0x80000000u) ? ~u : (u | 0x80000000u);   // monotone float->uint
    return ((u64)(~m) << 32) | (u32)idx;
}

// ---------- problem constants ----------
#define BATCH 8
#define CIN   64
#define FH    96
#define FW    320
#define KDET  50
#define NROI  400
#define CROI  69
#define HW    (FH*FW)
#define CHUNK 1920
#define NCHUNK 16

// ---------- workspace layout (float offsets) ----------
#define WS_HEAT 0L
#define WS_OFF2 737280L
#define WS_SIZ2 1228800L
#define WS_NH   1720320L
#define WS_S1S  2457600L
#define WS_S1I  2458800L
#define WS_CLS  2460000L
#define WS_BOX  2460400L
#define WS_ROI  2462400L
#define WS_HOUT 3814800L
#define WS_W1T  3827600L     // 147456 f32: hm conv1 [k=576][c=256] (exact strip)
#define WS_WB16 3975056L     // u16: 3 branches * [9][256][64] bf16
#define WS_W1H  4269968L     // u16: 4 heads * [9][3][256][32] bf16 = 884736 u16
#define WS_PAR  4905872L     // packed f32 params
#define WS_FLAG 4938960L     // int dtype flag

// param block sub-offsets
#define PB_CAL 0
#define PB_CRN 96
#define PB_MSZ 128
#define PB_BR0 144          // stride 1040: b1@0, w2@256 ([k][n]), b2@256+OC*256
#define PB_HD0 3264         // stride 7456

// ---------- output layout (element offsets) ----------
#define O_HEAT 0L
#define O_OFF2 737280L
#define O_SIZ2 1228800L
#define O_HEAD 1720320L
#define O_DEP  1729920L
#define O_OFF3 1730720L
#define O_S3D  1731520L
#define O_H3D  1732720L

// =====================================================================
// dtype detection
// =====================================================================
__global__ void kDetect(const void* __restrict__ feat, int* __restrict__ flag) {
    __shared__ int cnt;
    if (threadIdx.x == 0) cnt = 0;
    __syncthreads();
    u16 v = ((const u16*)feat)[threadIdx.x];     // 512 threads
    float f = b2f(v);
    u32 e = (v >> 7) & 0xFF;
    float a = fabsf(f);
    int sane = (e != 0xFF) && (f == 0.f || (a >= 1e-8f && a <= 1e4f));
    atomicAdd(&cnt, sane);
    __syncthreads();
    if (threadIdx.x == 0) *flag = (cnt >= 480) ? 1 : 0;
}

// =====================================================================
// Prep: weights
//  region 1: hm conv1 f32 [k=576][c=256]            (exact strip)
//  region 2: 3 branches bf16 [tap][n=256][ci=64]    (branch MFMA B)
//  region 3: 4 heads bf16 [tap][cs=3][oc=256][32]   (head MFMA B, ci zero-pad)
// =====================================================================
struct WPtrs { const void* bw[3]; const void* hw[4]; };

__global__ void kPrepW(WPtrs P, const int* __restrict__ flag,
                       float* __restrict__ w1t, u16* __restrict__ wb16,
                       u16* __restrict__ whb) {
    const int bf = *flag;
    int idx = blockIdx.x * 256 + threadIdx.x;
    if (idx < 147456) {
        int k = idx >> 8, c = idx & 255;
        w1t[idx] = gload(P.bw[0], (long)c * 576 + k, bf);
    } else if (idx < 589824) {
        int j = idx - 147456;
        int br = j / 147456, rem = j % 147456;
        int tap = rem / 16384, n = (rem >> 6) & 255, ci = rem & 63;
        wb16[j] = f2b(gload(P.bw[br], (long)n * 576 + ci * 9 + tap, bf));
    } else {
        int j = idx - 589824;               // < 884736
        int h = j / 221184, rem = j % 221184;
        int tap = rem / 24576, rem2 = rem % 24576;
        int cs = rem2 / 8192, rem3 = rem2 % 8192;
        int oc = rem3 >> 5, jj = rem3 & 31;
        int ci = cs * 32 + jj;
        u16 val = 0;
        if (ci < CROI) val = f2b(gload(P.hw[h], (long)oc * 621 + ci * 9 + tap, bf));
        whb[j] = val;
    }
}

// Prep: pack all small params to f32
struct Seg { const void* src; int n; int dst; };
struct Segs { Seg s[40]; };

__global__ void kPrepP(Segs S, const int* __restrict__ flag, float* __restrict__ par) {
    const int bf = *flag;
    Seg sg = S.s[blockIdx.x];
    for (int i = threadIdx.x; i < sg.n; i += 256)
        par[sg.dst + i] = gload(sg.src, i, bf);
}

// =====================================================================
// MFMA branch: conv3x3(64->256) as 9 shifted GEMMs + b1 + ReLU + 1x1 + b2
// =====================================================================
template<int OC>
__global__ __launch_bounds__(256, 2)
void kBranchM(const void* __restrict__ feat, const int* __restrict__ flag,
              const u16* __restrict__ wb,     // [9][256][64] bf16
              const float* __restrict__ bp,   // b1, w2[k][n], b2
              void* __restrict__ outb, long obase, float* __restrict__ outf) {
    __shared__ __align__(16) u16 a_lds[3][68][72];
    __shared__ __align__(16) u16 w_lds[256][72];
    __shared__ float red[4][64][OC];

    const int bfl = *flag;
    const int tid = threadIdx.x;
    const int wave = tid >> 6, lane = tid & 63;
    const int q = lane >> 4, n15 = lane & 15;
    const int x0 = blockIdx.x * 64, y = blockIdx.y, b = blockIdx.z;
    const int n0 = wave * 64;

    if (tid < 192) {
        const int ci = tid & 63, r = tid >> 6;
        const int gy = y - 1 + r;
        if (gy < 0 || gy >= FH) {
            for (int xi = 0; xi < 66; ++xi) a_lds[r][xi][ci] = 0;
        } else if (bfl) {
            const u16* rp = (const u16*)feat + ((long)((b << 6) | ci) * FH + gy) * FW;
            for (int j = 0; j < 10; ++j) {
                int xs0 = x0 - 8 + j * 8;
                u16 tmp[8];
                if (xs0 >= 0 && xs0 <= FW - 8)
                    *(uint4*)tmp = *(const uint4*)(rp + xs0);
                else
                    for (int e = 0; e < 8; ++e) {
                        int gx = xs0 + e;
                        tmp[e] = (gx >= 0 && gx < FW) ? rp[gx] : (u16)0;
                    }
                for (int e = 0; e < 8; ++e) {
                    int xi = xs0 + e - x0 + 1;
                    if (xi >= 0 && xi < 66) a_lds[r][xi][ci] = tmp[e];
                }
            }
        } else {
            const float* rp = (const float*)feat + ((long)((b << 6) | ci) * FH + gy) * FW;
            for (int j = 0; j < 18; ++j) {
                int xs0 = x0 - 4 + j * 4;
                float tmp[4];
                if (xs0 >= 0 && xs0 <= FW - 4)
                    *(float4*)tmp = *(const float4*)(rp + xs0);
                else
                    for (int e = 0; e < 4; ++e) {
                        int gx = xs0 + e;
                        tmp[e] = (gx >= 0 && gx < FW) ? rp[gx] : 0.f;
                    }
                for (int e = 0; e < 4; ++e) {
                    int xi = xs0 + e - x0 + 1;
                    if (xi >= 0 && xi < 66) a_lds[r][xi][ci] = f2b(tmp[e]);
                }
            }
        }
    }

    f32x4 acc[4][4];
#pragma unroll
    for (int i = 0; i < 4; ++i)
#pragma unroll
        for (int t = 0; t < 4; ++t) acc[i][t] = (f32x4){0.f, 0.f, 0.f, 0.f};

    for (int tap = 0; tap < 9; ++tap) {
        __syncthreads();
        const u16* wt = wb + tap * 16384;
        for (int i = tid; i < 2048; i += 256) {
            int n = i >> 3, c8 = i & 7;
            *(uint4*)&w_lds[n][c8 * 8] = *(const uint4*)(wt + n * 64 + c8 * 8);
        }
        __syncthreads();
        const int ky = tap / 3, kx = tap % 3;
#pragma unroll
        for (int s = 0; s < 2; ++s) {
            short8 afr[4], bfr[4];
#pragma unroll
            for (int i = 0; i < 4; ++i)
                afr[i] = *(const short8*)&a_lds[ky][i * 16 + n15 + kx][s * 32 + q * 8];
#pragma unroll
            for (int t = 0; t < 4; ++t)
                bfr[t] = *(const short8*)&w_lds[n0 + t * 16 + n15][s * 32 + q * 8];
#pragma unroll
            for (int i = 0; i < 4; ++i)
#pragma unroll
                for (int t = 0; t < 4; ++t)
                    acc[i][t] = __builtin_amdgcn_mfma_f32_16x16x32_bf16(
                        afr[i], bfr[t], acc[i][t], 0, 0, 0);
        }
    }

    float b1v[4], w2v[OC][4];
#pragma unroll
    for (int t = 0; t < 4; ++t) {
        int n = n0 + t * 16 + n15;
        b1v[t] = bp[n];
#pragma unroll
        for (int k = 0; k < OC; ++k) w2v[k][t] = bp[256 + k * 256 + n];
    }
#pragma unroll
    for (int i = 0; i < 4; ++i) {
#pragma unroll
        for (int r = 0; r < 4; ++r) {
            float pk[OC];
#pragma unroll
            for (int k = 0; k < OC; ++k) pk[k] = 0.f;
#pragma unroll
            for (int t = 0; t < 4; ++t) {
                float h = fmaxf(acc[i][t][r] + b1v[t], 0.f);
#pragma unroll
                for (int k = 0; k < OC; ++k) pk[k] = fmaf(h, w2v[k][t], pk[k]);
            }
#pragma unroll
            for (int k = 0; k < OC; ++k) {
                pk[k] += __shfl_xor(pk[k], 1);
                pk[k] += __shfl_xor(pk[k], 2);
                pk[k] += __shfl_xor(pk[k], 4);
                pk[k] += __shfl_xor(pk[k], 8);
            }
            if (n15 == 0) {
#pragma unroll
                for (int k = 0; k < OC; ++k)
                    red[wave][i * 16 + q * 4 + r][k] = pk[k];
            }
        }
    }
    __syncthreads();
    if (tid < 64 * OC) {
        int k = tid >> 6, px = tid & 63;
        float s = bp[256 + OC * 256 + k];
#pragma unroll
        for (int w = 0; w < 4; ++w) s += red[w][px][k];
        long o = (((long)b * OC + k) * FH + y) * FW + x0 + px;
        gstore(outb, obase + o, s, bfl);
        outf[o] = s;
    }
}

// =====================================================================
// Exact f32 strip (rows 0..4 of heat): NMS/topk decisions bit-match f32
// =====================================================================
union BrLds {
    float w[36 * 256];
    float part[32 * 3 * 64];
};

__global__ __launch_bounds__(256)
void kBranchX(const void* __restrict__ feat, const int* __restrict__ flag,
              const float* __restrict__ w1t, const float* __restrict__ bp,
              void* __restrict__ outb, long obase, float* __restrict__ outf) {
    __shared__ float in_lds[4][3][68];
    __shared__ BrLds u;
    const int bf = *flag;
    const int OC = 3;

    const int tid = threadIdx.x;
    const int xg = tid & 7, cg = tid >> 3;
    const int x0 = blockIdx.x * 64, y = blockIdx.y, b = blockIdx.z;
    const int c0 = cg * 8;

    float acc[8][8];
#pragma unroll
    for (int i = 0; i < 8; ++i)
#pragma unroll
        for (int j = 0; j < 8; ++j) acc[i][j] = 0.f;

    for (int chunk = 0; chunk < 16; ++chunk) {
        const int ci0 = chunk * 4;
        __syncthreads();
        for (int i = tid; i < 4 * 3 * 68; i += 256) {
            int xx = i % 68, t2 = i / 68;
            int r = t2 % 3, ci = t2 / 3;
            int gx = x0 - 1 + xx, gy = y - 1 + r;
            float v = 0.f;
            if (gx >= 0 && gx < FW && gy >= 0 && gy < FH)
                v = gload(feat, ((long)(b * CIN + ci0 + ci) * FH + gy) * FW + gx, bf);
            in_lds[ci][r][xx] = v;
        }
        {
            const float4* src = (const float4*)(w1t + (long)ci0 * 9 * 256);
            float4* dst = (float4*)u.w;
            for (int i = tid; i < 36 * 256 / 4; i += 256) dst[i] = src[i];
        }
        __syncthreads();
#pragma unroll
        for (int ci = 0; ci < 4; ++ci) {
#pragma unroll
            for (int ky = 0; ky < 3; ++ky) {
                const float* rowp = &in_lds[ci][ky][xg * 8];
                float inv[10];
                *(float4*)&inv[0] = *(const float4*)&rowp[0];
                *(float4*)&inv[4] = *(const float4*)&rowp[4];
                *(float2*)&inv[8] = *(const float2*)&rowp[8];
#pragma unroll
                for (int kx = 0; kx < 3; ++kx) {
                    const float* wp = &u.w[(ci * 9 + ky * 3 + kx) * 256 + c0];
                    float wv[8];
                    *(float4*)&wv[0] = *(const float4*)&wp[0];
                    *(float4*)&wv[4] = *(const float4*)&wp[4];
#pragma unroll
                    for (int cc = 0; cc < 8; ++cc)
#pragma unroll
                        for (int xx = 0; xx < 8; ++xx)
                            acc[cc][xx] = fmaf(wv[cc], inv[xx + kx], acc[cc][xx]);
                }
            }
        }
    }

#pragma unroll
    for (int cc = 0; cc < 8; ++cc) {
        float b1v = bp[c0 + cc];
#pragma unroll
        for (int xx = 0; xx < 8; ++xx)
            acc[cc][xx] = fmaxf(acc[cc][xx] + b1v, 0.f);
    }

    __syncthreads();
#pragma unroll
    for (int k = 0; k < OC; ++k) {
        float p[8];
#pragma unroll
        for (int xx = 0; xx < 8; ++xx) p[xx] = 0.f;
#pragma unroll
        for (int cc = 0; cc < 8; ++cc) {
            float wv = bp[256 + k * 256 + c0 + cc];
#pragma unroll
            for (int xx = 0; xx < 8; ++xx) p[xx] = fmaf(acc[cc][xx], wv, p[xx]);
        }
#pragma unroll
        for (int xx = 0; xx < 8; ++xx)
            u.part[(cg * OC + k) * 64 + xg * 8 + xx] = p[xx];
    }
    __syncthreads();
    for (int t = tid; t < OC * 64; t += 256) {
        int k = t >> 6, xx = t & 63;
        float s = bp[256 + OC * 256 + k];
#pragma unroll 8
        for (int g = 0; g < 32; ++g) s += u.part[(g * OC + k) * 64 + xx];
        long o = (((long)b * OC + k) * FH + y) * FW + x0 + xx;
        gstore(outb, obase + o, s, bf);
        outf[o] = s;
    }
}

// =====================================================================
// NMS
// =====================================================================
__global__ void kNms(const float* __restrict__ heat, float* __restrict__ nh) {
    int idx = blockIdx.x * 256 + threadIdx.x;
    if (idx >= 737280) return;
    int x = idx % FW, t = idx / FW;
    int yy = t % FH, bc = t / FH;
    const float* p = heat + (long)bc * HW;
    float v = p[yy * FW + x];
    float m = v;
    for (int dy = -1; dy <= 1; ++dy) {
        int ny = yy + dy;
        if (ny < 0 || ny >= FH) continue;
        for (int dx = -1; dx <= 1; ++dx) {
            int nx = x + dx;
            if (nx < 0 || nx >= FW) continue;
            m = fmaxf(m, p[ny * FW + nx]);
        }
    }
    nh[idx] = (v == m) ? v : 0.f;
}

// =====================================================================
// top-k stage A: per (bc, chunk) local top-50 via single-wave extraction.
// =====================================================================
__global__ __launch_bounds__(256)
void kTopA(float* __restrict__ nh) {
    __shared__ u64 keys[CHUNK];
    const int bc = blockIdx.x, ch = blockIdx.y;
    const int tid = threadIdx.x;
    const long base = (long)bc * HW + (long)ch * CHUNK;
    for (int i = tid; i < CHUNK; i += 256)
        keys[i] = packKey(nh[base + i], ch * CHUNK + i);
    __syncthreads();
    if (tid < 64) {
        const int lane = tid;
        u64* outp = (u64*)(nh + base);
        for (int it = 0; it < KDET; ++it) {
            u64 bk = ~0ULL; int bp = 0;
            for (int i = lane; i < CHUNK; i += 64) {
                u64 k = keys[i];
                if (k < bk) { bk = k; bp = i; }
            }
#pragma unroll
            for (int s = 32; s > 0; s >>= 1) {
                u64 k2 = __shfl_down(bk, s);
                int p2 = __shfl_down(bp, s);
                if (k2 < bk) { bk = k2; bp = p2; }
            }
            bk = __shfl(bk, 0);
            bp = __shfl(bp, 0);
            if (lane == 0) {
                outp[it] = bk;
                keys[bp] = ~0ULL;
            }
        }
    }
}

// =====================================================================
// top-k stage B: merge 16x50 chunk keys -> sorted per-(b,c) top-50
// =====================================================================
__global__ __launch_bounds__(64)
void kTopB(const float* __restrict__ nh, float* __restrict__ s1s,
           int* __restrict__ s1i) {
    __shared__ u64 keys[NCHUNK * KDET];
    const int bc = blockIdx.x, lane = threadIdx.x;
    for (int ch = 0; ch < NCHUNK; ++ch) {
        const u64* src = (const u64*)(nh + (long)bc * HW + (long)ch * CHUNK);
        if (lane < KDET) keys[ch * KDET + lane] = src[lane];
    }
    __syncthreads();
    for (int it = 0; it < KDET; ++it) {
        u64 bk = ~0ULL; int bp = 0;
        for (int i = lane; i < NCHUNK * KDET; i += 64) {
            u64 k = keys[i];
            if (k < bk) { bk = k; bp = i; }
        }
#pragma unroll
        for (int s = 32; s > 0; s >>= 1) {
            u64 k2 = __shfl_down(bk, s);
            int p2 = __shfl_down(bp, s);
            if (k2 < bk) { bk = k2; bp = p2; }
        }
        bk = __shfl(bk, 0);
        bp = __shfl(bp, 0);
        if (lane == 0) {
            u32 hm = ~(u32)(bk >> 32);
            u32 u = (hm & 0x80000000u) ? (hm & 0x7fffffffu) : ~hm;
            s1s[bc * KDET + it] = __uint_as_float(u);
            s1i[bc * KDET + it] = (int)(bk & 0xFFFFFFFFu);
            keys[bp] = ~0ULL;
        }
    }
}

// =====================================================================
// top-50 stage 2 + boxes
// =====================================================================
__global__ void kTop2(const float* __restrict__ s1s, const int* __restrict__ s1i,
                      const float* __restrict__ off2, const float* __restrict__ siz2,
                      float* __restrict__ boxes, int* __restrict__ clsArr) {
    const int b = blockIdx.x, t = threadIdx.x;    // 64 threads
    __shared__ float sc[150];
    for (int i = t; i < 150; i += 64) sc[i] = s1s[b * 150 + i];
    __syncthreads();
    for (int r = 0; r < KDET; ++r) {
        float bv = -INFINITY; int bp = 0x7fffffff;
        for (int i = t; i < 150; i += 64) {
            float v = sc[i];
            if (v > bv) { bv = v; bp = i; }
        }
        for (int s = 32; s > 0; s >>= 1) {
            float v2 = __shfl_down(bv, s);
            int   p2 = __shfl_down(bp, s);
            if (v2 > bv || (v2 == bv && p2 < bp)) { bv = v2; bp = p2; }
        }
        if (t == 0) {
            int cls = bp / KDET;
            int ind = s1i[b * 150 + bp];
            int n = b * KDET + r;
            clsArr[n] = cls;
            int x = ind % FW, yy = ind / FW;
            float cx = (float)x  + off2[(((long)b * 2 + 0) * FH + yy) * FW + x];
            float cy = (float)yy + off2[(((long)b * 2 + 1) * FH + yy) * FW + x];
            float w  = siz2[(((long)b * 2 + 0) * FH + yy) * FW + x];
            float h  = siz2[(((long)b * 2 + 1) * FH + yy) * FW + x];
            boxes[n * 5 + 0] = (float)b;
            boxes[n * 5 + 1] = cx - w * 0.5f;
            boxes[n * 5 + 2] = cy - h * 0.5f;
            boxes[n * 5 + 3] = cx + w * 0.5f;
            boxes[n * 5 + 4] = cy + h * 0.5f;
            sc[bp] = -INFINITY;
        }
        __syncthreads();
    }
}

// =====================================================================
// ROI align 7x7 (sr=2) + coord maps + one-hot -> roi_in f32
// =====================================================================
__global__ __launch_bounds__(256)
void kRoi(const void* __restrict__ feat, const int* __restrict__ flag,
          const float* __restrict__ boxes, const int* __restrict__ clsArr,
          const float* __restrict__ par, float* __restrict__ roi_in) {
    const int n = blockIdx.x, tid = threadIdx.x;
    const int bf = *flag;
    __shared__ int   x0s[14], x1s[14], y0s[14], y1s[14], vxs[14], vys[14];
    __shared__ float lxs[14], lys[14], cxs[7], cys[7];

    const float bx1 = boxes[n * 5 + 1], by1 = boxes[n * 5 + 2];
    const float bx2 = boxes[n * 5 + 3], by2 = boxes[n * 5 + 4];
    const int b = (int)boxes[n * 5 + 0];

    if (tid < 14) {
        float roi_w = fmaxf(bx2 - bx1, 1.f);
        float X = bx1 + (roi_w / 7.f) * ((tid + 0.5f) * 0.5f);
        vxs[tid] = (X > -1.f) && (X < (float)FW);
        float Xc = fminf(fmaxf(X, 0.f), (float)(FW - 1));
        int xi = (int)floorf(Xc);
        x0s[tid] = xi; x1s[tid] = min(xi + 1, FW - 1); lxs[tid] = Xc - (float)xi;
    } else if (tid >= 16 && tid < 30) {
        int i = tid - 16;
        float roi_h = fmaxf(by2 - by1, 1.f);
        float Y = by1 + (roi_h / 7.f) * ((i + 0.5f) * 0.5f);
        vys[i] = (Y > -1.f) && (Y < (float)FH);
        float Yc = fminf(fmaxf(Y, 0.f), (float)(FH - 1));
        int yi = (int)floorf(Yc);
        y0s[i] = yi; y1s[i] = min(yi + 1, FH - 1); lys[i] = Yc - (float)yi;
    } else if (tid >= 32 && tid < 46) {
        int j = tid - 32;
        const float* cal = par + PB_CAL + b * 12;
        float f_u = cal[0], c_u = cal[2], t03 = cal[3];
        float f_v = cal[5], c_v = cal[6], t13 = cal[7];
        float bxc = t03 / (-f_u), byc = t13 / (-f_v);
        const float* cr = par + PB_CRN + b * 4;
        float crx0 = cr[0], cry0 = cr[1], crx1 = cr[2], cry1 = cr[3];
        float sx = crx1 - crx0, sy = cry1 - cry0;
        float u1 = bx1 / (float)FW * sx + crx0, v1 = by1 / (float)FH * sy + cry0;
        float u2 = bx2 / (float)FW * sx + crx0, v2 = by2 / (float)FH * sy + cry0;
        float p1x = (u1 - c_u) / f_u + bxc, p1y = (v1 - c_v) / f_v + byc;
        float p2x = (u2 - c_u) / f_u + bxc, p2y = (v2 - c_v) / f_v + byc;
        if (j < 7) cxs[j] = p1x + ((float)j / 6.f) * (p2x - p1x);
        else       cys[j - 7] = p1y + ((float)(j - 7) / 6.f) * (p2y - p1y);
    }
    __syncthreads();

    for (int t = tid; t < CIN * 49; t += 256) {
        int c = t / 49, p = t % 49, oy = p / 7, ox = p % 7;
        long fb = ((long)b * CIN + c) * HW;
        float acc = 0.f;
#pragma unroll
        for (int dy = 0; dy < 2; ++dy) {
            int sy = oy * 2 + dy;
            float ly = lys[sy]; int yA = y0s[sy], yB = y1s[sy], vy = vys[sy];
#pragma unroll
            for (int dx = 0; dx < 2; ++dx) {
                int sx = ox * 2 + dx;
                float lx = lxs[sx]; int xA = x0s[sx], xB = x1s[sx];
                float v = (1.f - ly) * (1.f - lx) * gload(feat, fb + yA * FW + xA, bf)
                        + (1.f - ly) * lx         * gload(feat, fb + yA * FW + xB, bf)
                        + ly * (1.f - lx)         * gload(feat, fb + yB * FW + xA, bf)
                        + ly * lx                 * gload(feat, fb + yB * FW + xB, bf);
                if (!(vy && vxs[sx])) v = 0.f;
                acc += v;
            }
        }
        roi_in[((long)n * CROI + c) * 49 + p] = acc * 0.25f;
    }
    int cls = clsArr[n];
    for (int t = tid; t < 5 * 49; t += 256) {
        int ch = t / 49, p = t % 49, i = p / 7, j = p % 7;
        float v;
        if (ch == 0)      v = cxs[j];
        else if (ch == 1) v = cys[i];
        else              v = (cls == ch - 2) ? 1.f : 0.f;
        roi_in[((long)n * CROI + 64 + ch) * 49 + p] = v;
    }
}

// =====================================================================
// MFMA ROI head: conv3x3(69->256,pad1) as 9 taps x 3 k-steps GEMM
// D[pos 64(49 valid)][oc 256], then b1+BN+relu+mean(49)+1x1.
// Block = (head h, roi n), 256 thr = 4 waves; wave owns 64 oc.
// =====================================================================
__global__ __launch_bounds__(256, 2)
void kHeadM(const float* __restrict__ roi_in, const u16* __restrict__ whb,
            const float* __restrict__ par, float* __restrict__ head_out) {
    const int h = blockIdx.x, n = blockIdx.y, tid = threadIdx.x;
    const int wave = tid >> 6, lane = tid & 63;
    const int q = lane >> 4, n15 = lane & 15;
    const int ocArr[4] = {2, 2, 4, 24};
    const int offArr[4] = {0, 2, 4, 8};
    __shared__ __align__(16) u16 r_lds[9][9][96];    // padded roi, ci-contig
    __shared__ __align__(16) u16 w_lds[256][96];     // per-tap weights [oc][ci96]
    __shared__ float means[256];

    // zero r_lds (covers borders + ci>=69 pad)
    for (int i = tid; i < 9 * 9 * 96 / 8; i += 256)
        ((uint4*)r_lds)[i] = (uint4){0, 0, 0, 0};
    __syncthreads();
    const float* rp = roi_in + (long)n * CROI * 49;
    for (int i = tid; i < CROI * 49; i += 256) {
        int c = i / 49, p = i % 49;
        r_lds[p / 7 + 1][p % 7 + 1][c] = f2b(rp[i]);
    }

    // pos -> (oy,ox) per M-tile (clamped; invalid rows discarded later)
    int oyA[4], oxA[4];
#pragma unroll
    for (int i = 0; i < 4; ++i) {
        int pos = i * 16 + n15; if (pos > 48) pos = 48;
        oyA[i] = pos / 7; oxA[i] = pos % 7;
    }

    f32x4 acc[4][4];
#pragma unroll
    for (int i = 0; i < 4; ++i)
#pragma unroll
        for (int t = 0; t < 4; ++t) acc[i][t] = (f32x4){0.f, 0.f, 0.f, 0.f};

    for (int tap = 0; tap < 9; ++tap) {
        __syncthreads();   // w_lds reuse; first iter also guards r_lds fill
        const u16* wt = whb + ((long)h * 9 + tap) * 24576;   // [3][256][32]
        for (int i = tid; i < 3072; i += 256) {
            int cs = i >> 10, oc = (i & 1023) >> 2, seg = i & 3;
            *(uint4*)&w_lds[oc][cs * 32 + seg * 8] =
                *(const uint4*)(wt + ((cs << 8) + oc) * 32 + seg * 8);
        }
        __syncthreads();
        const int ky = tap / 3, kx = tap % 3;
#pragma unroll
        for (int cs = 0; cs < 3; ++cs) {
            short8 afr[4], bfr[4];
#pragma unroll
            for (int i = 0; i < 4; ++i)
                afr[i] = *(const short8*)&r_lds[oyA[i] + ky][oxA[i] + kx][cs * 32 + q * 8];
#pragma unroll
            for (int t = 0; t < 4; ++t)
                bfr[t] = *(const short8*)&w_lds[wave * 64 + t * 16 + n15][cs * 32 + q * 8];
#pragma unroll
            for (int i = 0; i < 4; ++i)
#pragma unroll
                for (int t = 0; t < 4; ++t)
                    acc[i][t] = __builtin_amdgcn_mfma_f32_16x16x32_bf16(
                        afr[i], bfr[t], acc[i][t], 0, 0, 0);
        }
    }

    // epilogue: b1 + BN + relu + masked mean over 49 positions
    const float* hb = par + PB_HD0 + h * 7456;
#pragma unroll
    for (int t = 0; t < 4; ++t) {
        int oc = wave * 64 + t * 16 + n15;
        float b1 = hb[oc], g = hb[256 + oc], be = hb[512 + oc];
        float m = hb[768 + oc], v = hb[1024 + oc];
        float scale = g / sqrtf(v + 1e-5f);
        float s = 0.f;
#pragma unroll
        for (int i = 0; i < 4; ++i)
#pragma unroll
            for (int r = 0; r < 4; ++r) {
                int pos = i * 16 + q * 4 + r;
                if (pos < 49)
                    s += fmaxf((acc[i][t][r] + b1 - m) * scale + be, 0.f);
            }
        s += __shfl_xor(s, 16);
        s += __shfl_xor(s, 32);
        if (q == 0) means[oc] = s / 49.f;
    }
    __syncthreads();

    // 1x1: each output k assigned to wave (k % 4 == wave)
    int oc_out = ocArr[h];
    const float* w2 = hb + 1280;
    for (int k = wave; k < oc_out; k += 4) {
        float s = 0.f;
        for (int c = lane; c < 256; c += 64) s += means[c] * w2[k * 256 + c];
#pragma unroll
        for (int off = 32; off > 0; off >>= 1) s += __shfl_down(s, off);
        if (lane == 0)
            head_out[(long)n * 32 + offArr[h] + k] = s + w2[oc_out * 256 + k];
    }
}

// =====================================================================
// Final scalar math + small outputs
// =====================================================================
__global__ void kFinal(const float* __restrict__ head_out, const float* __restrict__ boxes,
                       const int* __restrict__ clsArr, const float* __restrict__ par,
                       void* __restrict__ out, const int* __restrict__ flag) {
    int n = blockIdx.x * 256 + threadIdx.x;
    if (n >= NROI) return;
    const int bf = *flag;
    const float* ho = head_out + (long)n * 32;
    float dep0 = ho[0], dep1 = ho[1];
    int b = (int)boxes[n * 5 + 0];
    int cls = clsArr[n];

    for (int j = 0; j < 24; ++j) gstore(out, O_HEAD + n * 24 + j, ho[8 + j], bf);
    gstore(out, O_OFF3 + n * 2 + 0, ho[2], bf);
    gstore(out, O_OFF3 + n * 2 + 1, ho[3], bf);
    gstore(out, O_S3D + n * 3 + 0, ho[4], bf);
    gstore(out, O_S3D + n * 3 + 1, ho[5], bf);
    gstore(out, O_S3D + n * 3 + 2, ho[6], bf);
    gstore(out, O_H3D + n, ho[7], bf);

    float cry0 = par[PB_CRN + b * 4 + 1], cry1 = par[PB_CRN + b * 4 + 3];
    float sy = cry1 - cry0;
    float bi2 = boxes[n * 5 + 2] / (float)FH * sy + cry0;
    float bi4 = boxes[n * 5 + 4] / (float)FH * sy + cry0;
    float box_h = fmaxf(bi4 - bi2, 1.f);
    float f_u = par[PB_CAL + b * 12 + 0];
    float size3d0 = par[PB_MSZ + cls * 3 + 0] + ho[4];
    float depth_geo = size3d0 / box_h * f_u;
    float sig = 1.f / (1.f + expf(-dep0));
    float d0 = 1.f / (sig + 1e-6f) - 1.f + depth_geo;
    float dgls = ho[7] + 2.f * (logf(f_u) - logf(box_h));
    float mx = fmaxf(dep1, dgls);
    float lse = mx + logf(expf(dep1 - mx) + expf(dgls - mx));
    gstore(out, O_DEP + n * 2 + 0, d0, bf);
    gstore(out, O_DEP + n * 2 + 1, lse, bf);
}

// =====================================================================
extern "C" void kernel_launch(void* const* d_in, const int* in_sizes, int n_in,
                              void* d_out, int out_size, void* d_ws, size_t ws_size,
                              hipStream_t stream) {
    (void)in_sizes; (void)n_in; (void)out_size; (void)ws_size;
    float* ws = (float*)d_ws;
    float* par = ws + WS_PAR;
    int* flag = (int*)(ws + WS_FLAG);
    u16* wb16 = (u16*)(ws + WS_WB16);
    u16* whb  = (u16*)(ws + WS_W1H);
    const void* feat = d_in[0];

    kDetect<<<1, 512, 0, stream>>>(feat, flag);

    WPtrs WP;
    WP.bw[0] = d_in[4]; WP.bw[1] = d_in[8]; WP.bw[2] = d_in[12];
    WP.hw[0] = d_in[16]; WP.hw[1] = d_in[24]; WP.hw[2] = d_in[32]; WP.hw[3] = d_in[40];
    kPrepW<<<5760, 256, 0, stream>>>(WP, flag, ws + WS_W1T, wb16, whb);

    Segs SG; int si = 0;
    auto add = [&](const void* s, int n, int dst) {
        SG.s[si].src = s; SG.s[si].n = n; SG.s[si].dst = dst; ++si;
    };
    add(d_in[1], 96, PB_CAL); add(d_in[2], 32, PB_CRN); add(d_in[3], 9, PB_MSZ);
    const int ocb[3] = {3, 2, 2};
    for (int b = 0; b < 3; ++b) {
        int base = PB_BR0 + b * 1040;
        int i0 = 4 + 4 * b;
        add(d_in[i0 + 1], 256, base);
        add(d_in[i0 + 2], ocb[b] * 256, base + 256);
        add(d_in[i0 + 3], ocb[b], base + 256 + ocb[b] * 256);
    }
    const int och[4] = {2, 2, 4, 24};
    for (int h = 0; h < 4; ++h) {
        int base = PB_HD0 + h * 7456;
        int i0 = 16 + 8 * h;
        add(d_in[i0 + 1], 256, base);
        add(d_in[i0 + 2], 256, base + 256);
        add(d_in[i0 + 3], 256, base + 512);
        add(d_in[i0 + 4], 256, base + 768);
        add(d_in[i0 + 5], 256, base + 1024);
        add(d_in[i0 + 6], och[h] * 256, base + 1280);
        add(d_in[i0 + 7], och[h], base + 1280 + och[h] * 256);
    }
    kPrepP<<<si, 256, 0, stream>>>(SG, flag, par);

    // MFMA branches
    kBranchM<3><<<dim3(5, 96, 8), 256, 0, stream>>>(
        feat, flag, wb16, par + PB_BR0, d_out, O_HEAT, ws + WS_HEAT);
    kBranchM<2><<<dim3(5, 96, 8), 256, 0, stream>>>(
        feat, flag, wb16 + 147456, par + PB_BR0 + 1040, d_out, O_OFF2, ws + WS_OFF2);
    kBranchM<2><<<dim3(5, 96, 8), 256, 0, stream>>>(
        feat, flag, wb16 + 294912, par + PB_BR0 + 2080, d_out, O_SIZ2, ws + WS_SIZ2);

    // exact f32 strip for NMS/topk decision region (rows 0..4 of heat)
    kBranchX<<<dim3(5, 5, 8), 256, 0, stream>>>(
        feat, flag, ws + WS_W1T, par + PB_BR0, d_out, O_HEAT, ws + WS_HEAT);

    kNms<<<2880, 256, 0, stream>>>(ws + WS_HEAT, ws + WS_NH);
    kTopA<<<dim3(24, NCHUNK), 256, 0, stream>>>(ws + WS_NH);
    kTopB<<<24, 64, 0, stream>>>(ws + WS_NH, ws + WS_S1S, (int*)(ws + WS_S1I));
    kTop2<<<8, 64, 0, stream>>>(ws + WS_S1S, (int*)(ws + WS_S1I), ws + WS_OFF2,
                                ws + WS_SIZ2, ws + WS_BOX, (int*)(ws + WS_CLS));
    kRoi<<<400, 256, 0, stream>>>(feat, flag, ws + WS_BOX, (int*)(ws + WS_CLS),
                                  par, ws + WS_ROI);
    kHeadM<<<dim3(4, NROI), 256, 0, stream>>>(ws + WS_ROI, whb, par, ws + WS_HOUT);
    kFinal<<<2, 256, 0, stream>>>(ws + WS_HOUT, ws + WS_BOX, (int*)(ws + WS_CLS),
                                  par, d_out, flag);
}

// Round 6
// 1160.166 us; speedup vs baseline: 3.4107x; 1.1733x over previous
//
#include <hip/hip_runtime.h>
#include <math.h>

typedef unsigned short u16;
typedef unsigned int   u32;
typedef unsigned long long u64;
typedef __attribute__((ext_vector_type(8))) short short8;   // 8 bf16 (4 VGPR)
typedef __attribute__((ext_vector_type(4))) float f32x4;    // MFMA acc

// ---------- dtype helpers ----------
__device__ __forceinline__ float b2f(u16 v) { return __uint_as_float(((u32)v) << 16); }
__device__ __forceinline__ u16 f2b(float f) {
    u32 u = __float_as_uint(f);
    u32 r = (u + 0x7FFFu + ((u >> 16) & 1u)) >> 16;   // RNE
    return (u16)r;
}
__device__ __forceinline__ float gload(const void* p, long i, int bf) {
    return bf ? b2f(((const u16*)p)[i]) : ((const float*)p)[i];
}
__device__ __forceinline__ void gstore(void* p, long i, float v, int bf) {
    if (bf) ((u16*)p)[i] = f2b(v);
    else    ((float*)p)[i] = v;
}

// top-k key: smallest key = (largest value, then smallest index)
__device__ __forceinline__ u64 packKey(float v, int idx) {
    u32 u = __float_as_uint(v);
    u32 m = (u & 0x80000000u) ? ~u : (u | 0x80000000u);   // monotone float->uint
    return ((u64)(~m) << 32) | (u32)idx;
}

// ---------- problem constants ----------
#define BATCH 8
#define CIN   64
#define FH    96
#define FW    320
#define KDET  50
#define NROI  400
#define CROI  69
#define HW    (FH*FW)
#define CHUNK 1920
#define NCHUNK 16

// ---------- workspace layout (float offsets) ----------
#define WS_HEAT 0L
#define WS_OFF2 737280L
#define WS_SIZ2 1228800L
#define WS_NH   1720320L
#define WS_S1S  2457600L
#define WS_S1I  2458800L
#define WS_CLS  2460000L
#define WS_BOX  2460400L
#define WS_ROI  2462400L
#define WS_HOUT 3814800L
#define WS_W1T  3827600L     // 147456 f32: hm conv1 [k=576][c=256] (exact strip)
#define WS_WB16 3975056L     // u16: 3 branches * [9][256][64] bf16
#define WS_W1H  4269968L     // u16: 4 heads * [9][3][256][32] bf16
#define WS_PAR  4905872L     // packed f32 params
#define WS_FLAG 4938960L     // int dtype flag

// param block sub-offsets
#define PB_CAL 0
#define PB_CRN 96
#define PB_MSZ 128
#define PB_BR0 144          // stride 1040: b1@0, w2@256 ([k][n]), b2@256+OC*256
#define PB_HD0 3264         // stride 7456

// ---------- output layout (element offsets) ----------
#define O_HEAT 0L
#define O_OFF2 737280L
#define O_SIZ2 1228800L
#define O_HEAD 1720320L
#define O_DEP  1729920L
#define O_OFF3 1730720L
#define O_S3D  1731520L
#define O_H3D  1732720L

// =====================================================================
// dtype detection
// =====================================================================
__global__ void kDetect(const void* __restrict__ feat, int* __restrict__ flag) {
    __shared__ int cnt;
    if (threadIdx.x == 0) cnt = 0;
    __syncthreads();
    u16 v = ((const u16*)feat)[threadIdx.x];     // 512 threads
    float f = b2f(v);
    u32 e = (v >> 7) & 0xFF;
    float a = fabsf(f);
    int sane = (e != 0xFF) && (f == 0.f || (a >= 1e-8f && a <= 1e4f));
    atomicAdd(&cnt, sane);
    __syncthreads();
    if (threadIdx.x == 0) *flag = (cnt >= 480) ? 1 : 0;
}

// =====================================================================
// Prep: weights
// =====================================================================
struct WPtrs { const void* bw[3]; const void* hw[4]; };

__global__ void kPrepW(WPtrs P, const int* __restrict__ flag,
                       float* __restrict__ w1t, u16* __restrict__ wb16,
                       u16* __restrict__ whb) {
    const int bf = *flag;
    int idx = blockIdx.x * 256 + threadIdx.x;
    if (idx < 147456) {
        int k = idx >> 8, c = idx & 255;
        w1t[idx] = gload(P.bw[0], (long)c * 576 + k, bf);
    } else if (idx < 589824) {
        int j = idx - 147456;
        int br = j / 147456, rem = j % 147456;
        int tap = rem / 16384, n = (rem >> 6) & 255, ci = rem & 63;
        wb16[j] = f2b(gload(P.bw[br], (long)n * 576 + ci * 9 + tap, bf));
    } else {
        int j = idx - 589824;               // < 884736
        int h = j / 221184, rem = j % 221184;
        int tap = rem / 24576, rem2 = rem % 24576;
        int cs = rem2 / 8192, rem3 = rem2 % 8192;
        int oc = rem3 >> 5, jj = rem3 & 31;
        int ci = cs * 32 + jj;
        u16 val = 0;
        if (ci < CROI) val = f2b(gload(P.hw[h], (long)oc * 621 + ci * 9 + tap, bf));
        whb[j] = val;
    }
}

// Prep: pack all small params to f32
struct Seg { const void* src; int n; int dst; };
struct Segs { Seg s[40]; };

__global__ void kPrepP(Segs S, const int* __restrict__ flag, float* __restrict__ par) {
    const int bf = *flag;
    Seg sg = S.s[blockIdx.x];
    for (int i = threadIdx.x; i < sg.n; i += 256)
        par[sg.dst + i] = gload(sg.src, i, bf);
}

// =====================================================================
// Merged MFMA branch conv: all 3 branches, 512 thr, M=128 (2 rows x 64 x)
// conv3x3(64->256) as 9 shifted GEMMs + b1 + ReLU + 1x1(->oc) + b2
// grid (5, 48, 24); z = br*8 + b. Wave owns 32 n; 8 M-tiles x 2 N-tiles.
// =====================================================================
union B3U {
    u16   a[4][68][72];       // input rows y0-1..y0+2, x0-1..x0+64, 64ci (pad 72)
    float red[8][128][3];     // 1x1 partials per wave
};

__global__ __launch_bounds__(512, 4)
void kBranch3(const void* __restrict__ feat, const int* __restrict__ flag,
              const u16* __restrict__ wbAll,   // 3 * [9][256][64] bf16
              const float* __restrict__ bpAll, // par + PB_BR0, stride 1040
              void* __restrict__ outb, float* __restrict__ wsbase) {
    __shared__ __align__(16) B3U u;
    __shared__ __align__(16) u16 w_lds[256][72];

    const long obase[3] = {O_HEAT, O_OFF2, O_SIZ2};
    const long wfs[3]   = {WS_HEAT, WS_OFF2, WS_SIZ2};

    const int bfl = *flag;
    const int tid = threadIdx.x;
    const int wave = tid >> 6, lane = tid & 63;
    const int q = lane >> 4, n15 = lane & 15;
    const int x0 = blockIdx.x * 64, y0 = blockIdx.y * 2;
    const int br = blockIdx.z >> 3, b = blockIdx.z & 7;
    const int oc = (br == 0) ? 3 : 2;
    const u16* wb = wbAll + br * 147456;
    const float* bp = bpAll + br * 1040;

    // ---- stage input tile: rows y0-1..y0+2, x0-1..x0+64, 64 ci ----
    if (tid < 256) {
        const int ci = tid & 63, rr = tid >> 6;
        const int gy = y0 - 1 + rr;
        if (gy < 0 || gy >= FH) {
            for (int xi = 0; xi < 66; ++xi) u.a[rr][xi][ci] = 0;
        } else if (bfl) {
            const u16* rp = (const u16*)feat + ((long)((b << 6) | ci) * FH + gy) * FW;
            for (int j = 0; j < 10; ++j) {
                int xs0 = x0 - 8 + j * 8;
                u16 tmp[8];
                if (xs0 >= 0 && xs0 <= FW - 8)
                    *(uint4*)tmp = *(const uint4*)(rp + xs0);
                else
                    for (int e = 0; e < 8; ++e) {
                        int gx = xs0 + e;
                        tmp[e] = (gx >= 0 && gx < FW) ? rp[gx] : (u16)0;
                    }
                for (int e = 0; e < 8; ++e) {
                    int xi = xs0 + e - x0 + 1;
                    if (xi >= 0 && xi < 66) u.a[rr][xi][ci] = tmp[e];
                }
            }
        } else {
            const float* rp = (const float*)feat + ((long)((b << 6) | ci) * FH + gy) * FW;
            for (int j = 0; j < 18; ++j) {
                int xs0 = x0 - 4 + j * 4;
                float tmp[4];
                if (xs0 >= 0 && xs0 <= FW - 4)
                    *(float4*)tmp = *(const float4*)(rp + xs0);
                else
                    for (int e = 0; e < 4; ++e) {
                        int gx = xs0 + e;
                        tmp[e] = (gx >= 0 && gx < FW) ? rp[gx] : 0.f;
                    }
                for (int e = 0; e < 4; ++e) {
                    int xi = xs0 + e - x0 + 1;
                    if (xi >= 0 && xi < 66) u.a[rr][xi][ci] = f2b(tmp[e]);
                }
            }
        }
    }

    f32x4 acc[8][2];
#pragma unroll
    for (int i = 0; i < 8; ++i)
#pragma unroll
        for (int t = 0; t < 2; ++t) acc[i][t] = (f32x4){0.f, 0.f, 0.f, 0.f};

    // ---- K-loop: 9 taps x 2 k-steps (32 ci each) ----
    for (int tap = 0; tap < 9; ++tap) {
        __syncthreads();   // prior tap readers done (first iter: a_lds fill fence)
        const u16* wt = wb + tap * 16384;
        for (int i = tid; i < 2048; i += 512) {
            int n = i >> 3, c8 = i & 7;
            *(uint4*)&w_lds[n][c8 * 8] = *(const uint4*)(wt + n * 64 + c8 * 8);
        }
        __syncthreads();
        const int ky = tap / 3, kx = tap % 3;
#pragma unroll
        for (int s = 0; s < 2; ++s) {
            short8 bfr[2];
#pragma unroll
            for (int t = 0; t < 2; ++t)
                bfr[t] = *(const short8*)&w_lds[wave * 32 + t * 16 + n15][s * 32 + q * 8];
#pragma unroll
            for (int ig = 0; ig < 2; ++ig) {
                short8 afr[4];
#pragma unroll
                for (int i = 0; i < 4; ++i) {
                    int it = ig * 4 + i;
                    int r = it >> 2, xb = (it & 3) * 16;
                    afr[i] = *(const short8*)&u.a[r + ky][xb + n15 + kx][s * 32 + q * 8];
                }
#pragma unroll
                for (int i = 0; i < 4; ++i)
#pragma unroll
                    for (int t = 0; t < 2; ++t)
                        acc[ig * 4 + i][t] = __builtin_amdgcn_mfma_f32_16x16x32_bf16(
                            afr[i], bfr[t], acc[ig * 4 + i][t], 0, 0, 0);
            }
        }
    }

    // ---- epilogue: b1 + relu + 1x1 partials ----
    float b1v[2], w2v[3][2];
#pragma unroll
    for (int t = 0; t < 2; ++t) {
        int n = wave * 32 + t * 16 + n15;
        b1v[t] = bp[n];
#pragma unroll
        for (int k = 0; k < 3; ++k) w2v[k][t] = bp[256 + k * 256 + n];
    }
    __syncthreads();   // done reading u.a; reuse as red
#pragma unroll
    for (int i = 0; i < 8; ++i) {
#pragma unroll
        for (int r = 0; r < 4; ++r) {
            float pk[3];
#pragma unroll
            for (int k = 0; k < 3; ++k) pk[k] = 0.f;
#pragma unroll
            for (int t = 0; t < 2; ++t) {
                float h = fmaxf(acc[i][t][r] + b1v[t], 0.f);
#pragma unroll
                for (int k = 0; k < 3; ++k) pk[k] = fmaf(h, w2v[k][t], pk[k]);
            }
#pragma unroll
            for (int k = 0; k < 3; ++k) {
                pk[k] += __shfl_xor(pk[k], 1);
                pk[k] += __shfl_xor(pk[k], 2);
                pk[k] += __shfl_xor(pk[k], 4);
                pk[k] += __shfl_xor(pk[k], 8);
            }
            if (n15 == 0) {
                int m = i * 16 + q * 4 + r;
#pragma unroll
                for (int k = 0; k < 3; ++k) u.red[wave][m][k] = pk[k];
            }
        }
    }
    __syncthreads();
    float* outf = wsbase + wfs[br];
    for (int t2 = tid; t2 < oc * 128; t2 += 512) {
        int k = t2 >> 7, m = t2 & 127;
        int row = m >> 6, x = m & 63;
        float s = bp[256 + oc * 256 + k];
#pragma unroll
        for (int w = 0; w < 8; ++w) s += u.red[w][m][k];
        long o = (((long)b * oc + k) * FH + (y0 + row)) * FW + x0 + x;
        gstore(outb, obase[br] + o, s, bfl);
        outf[o] = s;
    }
}

// =====================================================================
// Exact f32 strip (rows 0..4 of heat): NMS/topk decisions bit-match f32
// =====================================================================
union BrLds {
    float w[36 * 256];
    float part[32 * 3 * 64];
};

__global__ __launch_bounds__(256)
void kBranchX(const void* __restrict__ feat, const int* __restrict__ flag,
              const float* __restrict__ w1t, const float* __restrict__ bp,
              void* __restrict__ outb, long obase, float* __restrict__ outf) {
    __shared__ float in_lds[4][3][68];
    __shared__ BrLds u;
    const int bf = *flag;
    const int OC = 3;

    const int tid = threadIdx.x;
    const int xg = tid & 7, cg = tid >> 3;
    const int x0 = blockIdx.x * 64, y = blockIdx.y, b = blockIdx.z;
    const int c0 = cg * 8;

    float acc[8][8];
#pragma unroll
    for (int i = 0; i < 8; ++i)
#pragma unroll
        for (int j = 0; j < 8; ++j) acc[i][j] = 0.f;

    for (int chunk = 0; chunk < 16; ++chunk) {
        const int ci0 = chunk * 4;
        __syncthreads();
        for (int i = tid; i < 4 * 3 * 68; i += 256) {
            int xx = i % 68, t2 = i / 68;
            int r = t2 % 3, ci = t2 / 3;
            int gx = x0 - 1 + xx, gy = y - 1 + r;
            float v = 0.f;
            if (gx >= 0 && gx < FW && gy >= 0 && gy < FH)
                v = gload(feat, ((long)(b * CIN + ci0 + ci) * FH + gy) * FW + gx, bf);
            in_lds[ci][r][xx] = v;
        }
        {
            const float4* src = (const float4*)(w1t + (long)ci0 * 9 * 256);
            float4* dst = (float4*)u.w;
            for (int i = tid; i < 36 * 256 / 4; i += 256) dst[i] = src[i];
        }
        __syncthreads();
#pragma unroll
        for (int ci = 0; ci < 4; ++ci) {
#pragma unroll
            for (int ky = 0; ky < 3; ++ky) {
                const float* rowp = &in_lds[ci][ky][xg * 8];
                float inv[10];
                *(float4*)&inv[0] = *(const float4*)&rowp[0];
                *(float4*)&inv[4] = *(const float4*)&rowp[4];
                *(float2*)&inv[8] = *(const float2*)&rowp[8];
#pragma unroll
                for (int kx = 0; kx < 3; ++kx) {
                    const float* wp = &u.w[(ci * 9 + ky * 3 + kx) * 256 + c0];
                    float wv[8];
                    *(float4*)&wv[0] = *(const float4*)&wp[0];
                    *(float4*)&wv[4] = *(const float4*)&wp[4];
#pragma unroll
                    for (int cc = 0; cc < 8; ++cc)
#pragma unroll
                        for (int xx = 0; xx < 8; ++xx)
                            acc[cc][xx] = fmaf(wv[cc], inv[xx + kx], acc[cc][xx]);
                }
            }
        }
    }

#pragma unroll
    for (int cc = 0; cc < 8; ++cc) {
        float b1v = bp[c0 + cc];
#pragma unroll
        for (int xx = 0; xx < 8; ++xx)
            acc[cc][xx] = fmaxf(acc[cc][xx] + b1v, 0.f);
    }

    __syncthreads();
#pragma unroll
    for (int k = 0; k < OC; ++k) {
        float p[8];
#pragma unroll
        for (int xx = 0; xx < 8; ++xx) p[xx] = 0.f;
#pragma unroll
        for (int cc = 0; cc < 8; ++cc) {
            float wv = bp[256 + k * 256 + c0 + cc];
#pragma unroll
            for (int xx = 0; xx < 8; ++xx) p[xx] = fmaf(acc[cc][xx], wv, p[xx]);
        }
#pragma unroll
        for (int xx = 0; xx < 8; ++xx)
            u.part[(cg * OC + k) * 64 + xg * 8 + xx] = p[xx];
    }
    __syncthreads();
    for (int t = tid; t < OC * 64; t += 256) {
        int k = t >> 6, xx = t & 63;
        float s = bp[256 + OC * 256 + k];
#pragma unroll 8
        for (int g = 0; g < 32; ++g) s += u.part[(g * OC + k) * 64 + xx];
        long o = (((long)b * OC + k) * FH + y) * FW + x0 + xx;
        gstore(outb, obase + o, s, bf);
        outf[o] = s;
    }
}

// =====================================================================
// NMS
// =====================================================================
__global__ void kNms(const float* __restrict__ heat, float* __restrict__ nh) {
    int idx = blockIdx.x * 256 + threadIdx.x;
    if (idx >= 737280) return;
    int x = idx % FW, t = idx / FW;
    int yy = t % FH, bc = t / FH;
    const float* p = heat + (long)bc * HW;
    float v = p[yy * FW + x];
    float m = v;
    for (int dy = -1; dy <= 1; ++dy) {
        int ny = yy + dy;
        if (ny < 0 || ny >= FH) continue;
        for (int dx = -1; dx <= 1; ++dx) {
            int nx = x + dx;
            if (nx < 0 || nx >= FW) continue;
            m = fmaxf(m, p[ny * FW + nx]);
        }
    }
    nh[idx] = (v == m) ? v : 0.f;
}

// =====================================================================
// top-k stage A: per (bc, chunk) local top-50 via single-wave extraction.
// =====================================================================
__global__ __launch_bounds__(256)
void kTopA(float* __restrict__ nh) {
    __shared__ u64 keys[CHUNK];
    const int bc = blockIdx.x, ch = blockIdx.y;
    const int tid = threadIdx.x;
    const long base = (long)bc * HW + (long)ch * CHUNK;
    for (int i = tid; i < CHUNK; i += 256)
        keys[i] = packKey(nh[base + i], ch * CHUNK + i);
    __syncthreads();
    if (tid < 64) {
        const int lane = tid;
        u64* outp = (u64*)(nh + base);
        for (int it = 0; it < KDET; ++it) {
            u64 bk = ~0ULL; int bp = 0;
            for (int i = lane; i < CHUNK; i += 64) {
                u64 k = keys[i];
                if (k < bk) { bk = k; bp = i; }
            }
#pragma unroll
            for (int s = 32; s > 0; s >>= 1) {
                u64 k2 = __shfl_down(bk, s);
                int p2 = __shfl_down(bp, s);
                if (k2 < bk) { bk = k2; bp = p2; }
            }
            bk = __shfl(bk, 0);
            bp = __shfl(bp, 0);
            if (lane == 0) {
                outp[it] = bk;
                keys[bp] = ~0ULL;
            }
        }
    }
}

// =====================================================================
// top-k stage B: merge 16x50 chunk keys -> sorted per-(b,c) top-50
// =====================================================================
__global__ __launch_bounds__(64)
void kTopB(const float* __restrict__ nh, float* __restrict__ s1s,
           int* __restrict__ s1i) {
    __shared__ u64 keys[NCHUNK * KDET];
    const int bc = blockIdx.x, lane = threadIdx.x;
    for (int ch = 0; ch < NCHUNK; ++ch) {
        const u64* src = (const u64*)(nh + (long)bc * HW + (long)ch * CHUNK);
        if (lane < KDET) keys[ch * KDET + lane] = src[lane];
    }
    __syncthreads();
    for (int it = 0; it < KDET; ++it) {
        u64 bk = ~0ULL; int bp = 0;
        for (int i = lane; i < NCHUNK * KDET; i += 64) {
            u64 k = keys[i];
            if (k < bk) { bk = k; bp = i; }
        }
#pragma unroll
        for (int s = 32; s > 0; s >>= 1) {
            u64 k2 = __shfl_down(bk, s);
            int p2 = __shfl_down(bp, s);
            if (k2 < bk) { bk = k2; bp = p2; }
        }
        bk = __shfl(bk, 0);
        bp = __shfl(bp, 0);
        if (lane == 0) {
            u32 hm = ~(u32)(bk >> 32);
            u32 u = (hm & 0x80000000u) ? (hm & 0x7fffffffu) : ~hm;
            s1s[bc * KDET + it] = __uint_as_float(u);
            s1i[bc * KDET + it] = (int)(bk & 0xFFFFFFFFu);
            keys[bp] = ~0ULL;
        }
    }
}

// =====================================================================
// top-50 stage 2 + boxes
// =====================================================================
__global__ void kTop2(const float* __restrict__ s1s, const int* __restrict__ s1i,
                      const float* __restrict__ off2, const float* __restrict__ siz2,
                      float* __restrict__ boxes, int* __restrict__ clsArr) {
    const int b = blockIdx.x, t = threadIdx.x;    // 64 threads
    __shared__ float sc[150];
    for (int i = t; i < 150; i += 64) sc[i] = s1s[b * 150 + i];
    __syncthreads();
    for (int r = 0; r < KDET; ++r) {
        float bv = -INFINITY; int bp = 0x7fffffff;
        for (int i = t; i < 150; i += 64) {
            float v = sc[i];
            if (v > bv) { bv = v; bp = i; }
        }
        for (int s = 32; s > 0; s >>= 1) {
            float v2 = __shfl_down(bv, s);
            int   p2 = __shfl_down(bp, s);
            if (v2 > bv || (v2 == bv && p2 < bp)) { bv = v2; bp = p2; }
        }
        if (t == 0) {
            int cls = bp / KDET;
            int ind = s1i[b * 150 + bp];
            int n = b * KDET + r;
            clsArr[n] = cls;
            int x = ind % FW, yy = ind / FW;
            float cx = (float)x  + off2[(((long)b * 2 + 0) * FH + yy) * FW + x];
            float cy = (float)yy + off2[(((long)b * 2 + 1) * FH + yy) * FW + x];
            float w  = siz2[(((long)b * 2 + 0) * FH + yy) * FW + x];
            float h  = siz2[(((long)b * 2 + 1) * FH + yy) * FW + x];
            boxes[n * 5 + 0] = (float)b;
            boxes[n * 5 + 1] = cx - w * 0.5f;
            boxes[n * 5 + 2] = cy - h * 0.5f;
            boxes[n * 5 + 3] = cx + w * 0.5f;
            boxes[n * 5 + 4] = cy + h * 0.5f;
            sc[bp] = -INFINITY;
        }
        __syncthreads();
    }
}

// =====================================================================
// ROI align 7x7 (sr=2) + coord maps + one-hot -> roi_in f32
// =====================================================================
__global__ __launch_bounds__(256)
void kRoi(const void* __restrict__ feat, const int* __restrict__ flag,
          const float* __restrict__ boxes, const int* __restrict__ clsArr,
          const float* __restrict__ par, float* __restrict__ roi_in) {
    const int n = blockIdx.x, tid = threadIdx.x;
    const int bf = *flag;
    __shared__ int   x0s[14], x1s[14], y0s[14], y1s[14], vxs[14], vys[14];
    __shared__ float lxs[14], lys[14], cxs[7], cys[7];

    const float bx1 = boxes[n * 5 + 1], by1 = boxes[n * 5 + 2];
    const float bx2 = boxes[n * 5 + 3], by2 = boxes[n * 5 + 4];
    const int b = (int)boxes[n * 5 + 0];

    if (tid < 14) {
        float roi_w = fmaxf(bx2 - bx1, 1.f);
        float X = bx1 + (roi_w / 7.f) * ((tid + 0.5f) * 0.5f);
        vxs[tid] = (X > -1.f) && (X < (float)FW);
        float Xc = fminf(fmaxf(X, 0.f), (float)(FW - 1));
        int xi = (int)floorf(Xc);
        x0s[tid] = xi; x1s[tid] = min(xi + 1, FW - 1); lxs[tid] = Xc - (float)xi;
    } else if (tid >= 16 && tid < 30) {
        int i = tid - 16;
        float roi_h = fmaxf(by2 - by1, 1.f);
        float Y = by1 + (roi_h / 7.f) * ((i + 0.5f) * 0.5f);
        vys[i] = (Y > -1.f) && (Y < (float)FH);
        float Yc = fminf(fmaxf(Y, 0.f), (float)(FH - 1));
        int yi = (int)floorf(Yc);
        y0s[i] = yi; y1s[i] = min(yi + 1, FH - 1); lys[i] = Yc - (float)yi;
    } else if (tid >= 32 && tid < 46) {
        int j = tid - 32;
        const float* cal = par + PB_CAL + b * 12;
        float f_u = cal[0], c_u = cal[2], t03 = cal[3];
        float f_v = cal[5], c_v = cal[6], t13 = cal[7];
        float bxc = t03 / (-f_u), byc = t13 / (-f_v);
        const float* cr = par + PB_CRN + b * 4;
        float crx0 = cr[0], cry0 = cr[1], crx1 = cr[2], cry1 = cr[3];
        float sx = crx1 - crx0, sy = cry1 - cry0;
        float u1 = bx1 / (float)FW * sx + crx0, v1 = by1 / (float)FH * sy + cry0;
        float u2 = bx2 / (float)FW * sx + crx0, v2 = by2 / (float)FH * sy + cry0;
        float p1x = (u1 - c_u) / f_u + bxc, p1y = (v1 - c_v) / f_v + byc;
        float p2x = (u2 - c_u) / f_u + bxc, p2y = (v2 - c_v) / f_v + byc;
        if (j < 7) cxs[j] = p1x + ((float)j / 6.f) * (p2x - p1x);
        else       cys[j - 7] = p1y + ((float)(j - 7) / 6.f) * (p2y - p1y);
    }
    __syncthreads();

    for (int t = tid; t < CIN * 49; t += 256) {
        int c = t / 49, p = t % 49, oy = p / 7, ox = p % 7;
        long fb = ((long)b * CIN + c) * HW;
        float acc = 0.f;
#pragma unroll
        for (int dy = 0; dy < 2; ++dy) {
            int sy = oy * 2 + dy;
            float ly = lys[sy]; int yA = y0s[sy], yB = y1s[sy], vy = vys[sy];
#pragma unroll
            for (int dx = 0; dx < 2; ++dx) {
                int sx = ox * 2 + dx;
                float lx = lxs[sx]; int xA = x0s[sx], xB = x1s[sx];
                float v = (1.f - ly) * (1.f - lx) * gload(feat, fb + yA * FW + xA, bf)
                        + (1.f - ly) * lx         * gload(feat, fb + yA * FW + xB, bf)
                        + ly * (1.f - lx)         * gload(feat, fb + yB * FW + xA, bf)
                        + ly * lx                 * gload(feat, fb + yB * FW + xB, bf);
                if (!(vy && vxs[sx])) v = 0.f;
                acc += v;
            }
        }
        roi_in[((long)n * CROI + c) * 49 + p] = acc * 0.25f;
    }
    int cls = clsArr[n];
    for (int t = tid; t < 5 * 49; t += 256) {
        int ch = t / 49, p = t % 49, i = p / 7, j = p % 7;
        float v;
        if (ch == 0)      v = cxs[j];
        else if (ch == 1) v = cys[i];
        else              v = (cls == ch - 2) ? 1.f : 0.f;
        roi_in[((long)n * CROI + 64 + ch) * 49 + p] = v;
    }
}

// =====================================================================
// MFMA ROI head: conv3x3(69->256,pad1) as 9 taps x 3 k-steps GEMM
// =====================================================================
__global__ __launch_bounds__(256, 2)
void kHeadM(const float* __restrict__ roi_in, const u16* __restrict__ whb,
            const float* __restrict__ par, float* __restrict__ head_out) {
    const int h = blockIdx.x, n = blockIdx.y, tid = threadIdx.x;
    const int wave = tid >> 6, lane = tid & 63;
    const int q = lane >> 4, n15 = lane & 15;
    const int ocArr[4] = {2, 2, 4, 24};
    const int offArr[4] = {0, 2, 4, 8};
    __shared__ __align__(16) u16 r_lds[9][9][96];    // padded roi, ci-contig
    __shared__ __align__(16) u16 w_lds[256][96];     // per-tap weights [oc][ci96]
    __shared__ float means[256];

    for (int i = tid; i < 9 * 9 * 96 / 8; i += 256)
        ((uint4*)r_lds)[i] = (uint4){0, 0, 0, 0};
    __syncthreads();
    const float* rp = roi_in + (long)n * CROI * 49;
    for (int i = tid; i < CROI * 49; i += 256) {
        int c = i / 49, p = i % 49;
        r_lds[p / 7 + 1][p % 7 + 1][c] = f2b(rp[i]);
    }

    int oyA[4], oxA[4];
#pragma unroll
    for (int i = 0; i < 4; ++i) {
        int pos = i * 16 + n15; if (pos > 48) pos = 48;
        oyA[i] = pos / 7; oxA[i] = pos % 7;
    }

    f32x4 acc[4][4];
#pragma unroll
    for (int i = 0; i < 4; ++i)
#pragma unroll
        for (int t = 0; t < 4; ++t) acc[i][t] = (f32x4){0.f, 0.f, 0.f, 0.f};

    for (int tap = 0; tap < 9; ++tap) {
        __syncthreads();
        const u16* wt = whb + ((long)h * 9 + tap) * 24576;   // [3][256][32]
        for (int i = tid; i < 3072; i += 256) {
            int cs = i >> 10, oc = (i & 1023) >> 2, seg = i & 3;
            *(uint4*)&w_lds[oc][cs * 32 + seg * 8] =
                *(const uint4*)(wt + ((cs << 8) + oc) * 32 + seg * 8);
        }
        __syncthreads();
        const int ky = tap / 3, kx = tap % 3;
#pragma unroll
        for (int cs = 0; cs < 3; ++cs) {
            short8 afr[4], bfr[4];
#pragma unroll
            for (int i = 0; i < 4; ++i)
                afr[i] = *(const short8*)&r_lds[oyA[i] + ky][oxA[i] + kx][cs * 32 + q * 8];
#pragma unroll
            for (int t = 0; t < 4; ++t)
                bfr[t] = *(const short8*)&w_lds[wave * 64 + t * 16 + n15][cs * 32 + q * 8];
#pragma unroll
            for (int i = 0; i < 4; ++i)
#pragma unroll
                for (int t = 0; t < 4; ++t)
                    acc[i][t] = __builtin_amdgcn_mfma_f32_16x16x32_bf16(
                        afr[i], bfr[t], acc[i][t], 0, 0, 0);
        }
    }

    const float* hb = par + PB_HD0 + h * 7456;
#pragma unroll
    for (int t = 0; t < 4; ++t) {
        int oc = wave * 64 + t * 16 + n15;
        float b1 = hb[oc], g = hb[256 + oc], be = hb[512 + oc];
        float m = hb[768 + oc], v = hb[1024 + oc];
        float scale = g / sqrtf(v + 1e-5f);
        float s = 0.f;
#pragma unroll
        for (int i = 0; i < 4; ++i)
#pragma unroll
            for (int r = 0; r < 4; ++r) {
                int pos = i * 16 + q * 4 + r;
                if (pos < 49)
                    s += fmaxf((acc[i][t][r] + b1 - m) * scale + be, 0.f);
            }
        s += __shfl_xor(s, 16);
        s += __shfl_xor(s, 32);
        if (q == 0) means[oc] = s / 49.f;
    }
    __syncthreads();

    int oc_out = ocArr[h];
    const float* w2 = hb + 1280;
    for (int k = wave; k < oc_out; k += 4) {
        float s = 0.f;
        for (int c = lane; c < 256; c += 64) s += means[c] * w2[k * 256 + c];
#pragma unroll
        for (int off = 32; off > 0; off >>= 1) s += __shfl_down(s, off);
        if (lane == 0)
            head_out[(long)n * 32 + offArr[h] + k] = s + w2[oc_out * 256 + k];
    }
}

// =====================================================================
// Final scalar math + small outputs
// =====================================================================
__global__ void kFinal(const float* __restrict__ head_out, const float* __restrict__ boxes,
                       const int* __restrict__ clsArr, const float* __restrict__ par,
                       void* __restrict__ out, const int* __restrict__ flag) {
    int n = blockIdx.x * 256 + threadIdx.x;
    if (n >= NROI) return;
    const int bf = *flag;
    const float* ho = head_out + (long)n * 32;
    float dep0 = ho[0], dep1 = ho[1];
    int b = (int)boxes[n * 5 + 0];
    int cls = clsArr[n];

    for (int j = 0; j < 24; ++j) gstore(out, O_HEAD + n * 24 + j, ho[8 + j], bf);
    gstore(out, O_OFF3 + n * 2 + 0, ho[2], bf);
    gstore(out, O_OFF3 + n * 2 + 1, ho[3], bf);
    gstore(out, O_S3D + n * 3 + 0, ho[4], bf);
    gstore(out, O_S3D + n * 3 + 1, ho[5], bf);
    gstore(out, O_S3D + n * 3 + 2, ho[6], bf);
    gstore(out, O_H3D + n, ho[7], bf);

    float cry0 = par[PB_CRN + b * 4 + 1], cry1 = par[PB_CRN + b * 4 + 3];
    float sy = cry1 - cry0;
    float bi2 = boxes[n * 5 + 2] / (float)FH * sy + cry0;
    float bi4 = boxes[n * 5 + 4] / (float)FH * sy + cry0;
    float box_h = fmaxf(bi4 - bi2, 1.f);
    float f_u = par[PB_CAL + b * 12 + 0];
    float size3d0 = par[PB_MSZ + cls * 3 + 0] + ho[4];
    float depth_geo = size3d0 / box_h * f_u;
    float sig = 1.f / (1.f + expf(-dep0));
    float d0 = 1.f / (sig + 1e-6f) - 1.f + depth_geo;
    float dgls = ho[7] + 2.f * (logf(f_u) - logf(box_h));
    float mx = fmaxf(dep1, dgls);
    float lse = mx + logf(expf(dep1 - mx) + expf(dgls - mx));
    gstore(out, O_DEP + n * 2 + 0, d0, bf);
    gstore(out, O_DEP + n * 2 + 1, lse, bf);
}

// =====================================================================
extern "C" void kernel_launch(void* const* d_in, const int* in_sizes, int n_in,
                              void* d_out, int out_size, void* d_ws, size_t ws_size,
                              hipStream_t stream) {
    (void)in_sizes; (void)n_in; (void)out_size; (void)ws_size;
    float* ws = (float*)d_ws;
    float* par = ws + WS_PAR;
    int* flag = (int*)(ws + WS_FLAG);
    u16* wb16 = (u16*)(ws + WS_WB16);
    u16* whb  = (u16*)(ws + WS_W1H);
    const void* feat = d_in[0];

    kDetect<<<1, 512, 0, stream>>>(feat, flag);

    WPtrs WP;
    WP.bw[0] = d_in[4]; WP.bw[1] = d_in[8]; WP.bw[2] = d_in[12];
    WP.hw[0] = d_in[16]; WP.hw[1] = d_in[24]; WP.hw[2] = d_in[32]; WP.hw[3] = d_in[40];
    kPrepW<<<5760, 256, 0, stream>>>(WP, flag, ws + WS_W1T, wb16, whb);

    Segs SG; int si = 0;
    auto add = [&](const void* s, int n, int dst) {
        SG.s[si].src = s; SG.s[si].n = n; SG.s[si].dst = dst; ++si;
    };
    add(d_in[1], 96, PB_CAL); add(d_in[2], 32, PB_CRN); add(d_in[3], 9, PB_MSZ);
    const int ocb[3] = {3, 2, 2};
    for (int b = 0; b < 3; ++b) {
        int base = PB_BR0 + b * 1040;
        int i0 = 4 + 4 * b;
        add(d_in[i0 + 1], 256, base);
        add(d_in[i0 + 2], ocb[b] * 256, base + 256);
        add(d_in[i0 + 3], ocb[b], base + 256 + ocb[b] * 256);
    }
    const int och[4] = {2, 2, 4, 24};
    for (int h = 0; h < 4; ++h) {
        int base = PB_HD0 + h * 7456;
        int i0 = 16 + 8 * h;
        add(d_in[i0 + 1], 256, base);
        add(d_in[i0 + 2], 256, base + 256);
        add(d_in[i0 + 3], 256, base + 512);
        add(d_in[i0 + 4], 256, base + 768);
        add(d_in[i0 + 5], 256, base + 1024);
        add(d_in[i0 + 6], och[h] * 256, base + 1280);
        add(d_in[i0 + 7], och[h], base + 1280 + och[h] * 256);
    }
    kPrepP<<<si, 256, 0, stream>>>(SG, flag, par);

    // merged MFMA branches (all 3 in one dispatch)
    kBranch3<<<dim3(5, 48, 24), 512, 0, stream>>>(
        feat, flag, wb16, par + PB_BR0, d_out, ws);

    // exact f32 strip for NMS/topk decision region (rows 0..4 of heat)
    kBranchX<<<dim3(5, 5, 8), 256, 0, stream>>>(
        feat, flag, ws + WS_W1T, par + PB_BR0, d_out, O_HEAT, ws + WS_HEAT);

    kNms<<<2880, 256, 0, stream>>>(ws + WS_HEAT, ws + WS_NH);
    kTopA<<<dim3(24, NCHUNK), 256, 0, stream>>>(ws + WS_NH);
    kTopB<<<24, 64, 0, stream>>>(ws + WS_NH, ws + WS_S1S, (int*)(ws + WS_S1I));
    kTop2<<<8, 64, 0, stream>>>(ws + WS_S1S, (int*)(ws + WS_S1I), ws + WS_OFF2,
                                ws + WS_SIZ2, ws + WS_BOX, (int*)(ws + WS_CLS));
    kRoi<<<400, 256, 0, stream>>>(feat, flag, ws + WS_BOX, (int*)(ws + WS_CLS),
                                  par, ws + WS_ROI);
    kHeadM<<<dim3(4, NROI), 256, 0, stream>>>(ws + WS_ROI, whb, par, ws + WS_HOUT);
    kFinal<<<2, 256, 0, stream>>>(ws + WS_HOUT, ws + WS_BOX, (int*)(ws + WS_CLS),
                                  par, d_out, flag);
}